// Round 8
// baseline (570.588 us; speedup 1.0000x reference)
//
#include <hip/hip_runtime.h>
#include <hip/hip_bf16.h>
#include <cstdint>
#include <cstddef>

// ---------------------------------------------------------------------------
// MeshMultiHeadHodgeLaplaceAttention  (b=2, n=2048, m=6144, k=4096, D=256, H=8)
//
//   up:   T1 = d_1 @ eV ; *f_hval ; T2 = d_1^T @ T1s ; (*einv_hval in combine)
//   down: Y0 = eV*e_hval ; T3 = d_0^T @ Y0 ; *1/(v_hval+eps) ; T4 = d_0 @ T3s
//   out = (T2*einv_hval + T4) @ W_o
//
// Precision (validated R3-R7, absmax=256 = bf16 ulp floor at out peak):
// v_hval replicates numpy fp32 bit-exactly; amplified chain split-bf16
// (hi/lo, 3 MFMA); up branch plain bf16.
//
// R8: the four incidence GEMMs (all-bf16 operands) move to the m97 recipe -
// global_load_lds width-16 staging into unpadded [128][32] LDS, 2 barriers.
// ---------------------------------------------------------------------------

typedef __attribute__((ext_vector_type(4))) float f32x4;
typedef __attribute__((ext_vector_type(4))) unsigned short u16x4;
typedef __attribute__((ext_vector_type(8))) unsigned short u16x8;
typedef __attribute__((ext_vector_type(8))) __bf16 bf16x8;

static __device__ __forceinline__ unsigned short f2bf(float f) {
  uint32_t u = __builtin_bit_cast(uint32_t, f);
  uint32_t r = (u + 0x7FFFu + ((u >> 16) & 1u)) >> 16;  // RNE
  return (unsigned short)r;
}
static __device__ __forceinline__ float bf2f(unsigned short h) {
  return __builtin_bit_cast(float, (uint32_t)h << 16);
}

// async global->LDS, 16 B per lane; lds base must be wave-uniform.
static __device__ __forceinline__ void gload16(const unsigned short* g,
                                               unsigned short* l) {
  __builtin_amdgcn_global_load_lds(
      (const __attribute__((address_space(1))) void*)g,
      (__attribute__((address_space(3))) void*)l, 16, 0, 0);
}

// ---------------------------------------------------------------------------
// gemm_bb: C[M x NC] = A[M x K] * B[N x K]^T-layout; ALL operands bf16
// (hi and optional lo), natural [row][K] layout. global_load_lds staging
// (m97 recipe): unpadded [128][32] LDS, per-lane global addr, wave-uniform
// LDS base, 2 barriers/K-step. Split-K via blockIdx.z = batch*S + split.
// ---------------------------------------------------------------------------
template <bool SPLIT, bool XFAST>
__global__ __launch_bounds__(256) void gemm_bb(
    const unsigned short* __restrict__ Ah, const unsigned short* __restrict__ Al,
    const unsigned short* __restrict__ Bh, const unsigned short* __restrict__ Bl,
    float* __restrict__ C, int K, int ldA, int ldB, int S,
    long long sA, long long sB, long long sC) {
  const int z = blockIdx.z;
  const int batch = z / S, split = z - batch * S;
  Ah += (long long)batch * sA;
  Bh += (long long)batch * sB;
  if constexpr (SPLIT) { Al += (long long)batch * sA; Bl += (long long)batch * sB; }
  C += (long long)z * sC;

  // XCD-bijective swizzle
  const int gx = gridDim.x, gy = gridDim.y;
  const int nwg = gx * gy;
  const int wid = blockIdx.x + gx * blockIdx.y;
  const int q = nwg >> 3, r = nwg & 7;
  const int xcd = wid & 7, posn = wid >> 3;
  const int swz = (xcd < r ? xcd * (q + 1) : r * (q + 1) + (xcd - r) * q) + posn;
  int mt, nt;
  if constexpr (XFAST) { mt = swz % gx; nt = swz / gx; }
  else                 { mt = swz / gy; nt = swz - mt * gy; }
  const int m0 = mt * 128, n0 = nt * 128;
  const int NC = gy << 7;

  const int kLen = K / S, k0base = split * kLen;
  constexpr int NBUF = SPLIT ? 4 : 2;
  __shared__ unsigned short lds[NBUF][128][32];  // [0]=Ah [1]=Bh [2]=Al [3]=Bl

  const int t = threadIdx.x;
  const int w = t >> 6, lane = t & 63;
  const int wr = w >> 1, wc = w & 1;
  const int lr = lane & 15, kq = lane >> 4;
  const int rS = lane >> 2;            // staging row within 16-row block
  const int cS = (lane & 3) * 8;       // staging halfword offset

  f32x4 acc[4][4] = {};

  for (int kk = 0; kk < kLen; kk += 32) {
    const int kb = k0base + kk;
    #pragma unroll
    for (int c = 0; c < 2; ++c) {
      const int rb = (w * 2 + c) * 16;        // 16-row block base
      const int row = rb + rS;
      gload16(Ah + (size_t)(m0 + row) * ldA + kb + cS, &lds[0][rb][0]);
      gload16(Bh + (size_t)(n0 + row) * ldB + kb + cS, &lds[1][rb][0]);
      if constexpr (SPLIT) {
        gload16(Al + (size_t)(m0 + row) * ldA + kb + cS, &lds[2][rb][0]);
        gload16(Bl + (size_t)(n0 + row) * ldB + kb + cS, &lds[3][rb][0]);
      }
    }
    __syncthreads();  // drains vmcnt -> LDS tiles ready

    bf16x8 ah[4], bh[4], al[4], bl[4];
    #pragma unroll
    for (int i = 0; i < 4; ++i) {
      ah[i] = __builtin_bit_cast(bf16x8, *(const u16x8*)&lds[0][wr * 64 + i * 16 + lr][kq * 8]);
      bh[i] = __builtin_bit_cast(bf16x8, *(const u16x8*)&lds[1][wc * 64 + i * 16 + lr][kq * 8]);
      if constexpr (SPLIT) {
        al[i] = __builtin_bit_cast(bf16x8, *(const u16x8*)&lds[2][wr * 64 + i * 16 + lr][kq * 8]);
        bl[i] = __builtin_bit_cast(bf16x8, *(const u16x8*)&lds[3][wc * 64 + i * 16 + lr][kq * 8]);
      }
    }
    #pragma unroll
    for (int i = 0; i < 4; ++i)
      #pragma unroll
      for (int j = 0; j < 4; ++j) {
        acc[i][j] = __builtin_amdgcn_mfma_f32_16x16x32_bf16(ah[i], bh[j], acc[i][j], 0, 0, 0);
        if constexpr (SPLIT) {
          acc[i][j] = __builtin_amdgcn_mfma_f32_16x16x32_bf16(ah[i], bl[j], acc[i][j], 0, 0, 0);
          acc[i][j] = __builtin_amdgcn_mfma_f32_16x16x32_bf16(al[i], bh[j], acc[i][j], 0, 0, 0);
        }
      }
    __syncthreads();  // all reads done before next stage overwrites
  }

  // epilogue: D mapping col = lane&15, row = (lane>>4)*4 + q
  #pragma unroll
  for (int i = 0; i < 4; ++i)
    #pragma unroll
    for (int j = 0; j < 4; ++j) {
      float* cp = C + (size_t)(m0 + wr * 64 + i * 16 + kq * 4) * NC + n0 + wc * 64 + j * 16 + lr;
      #pragma unroll
      for (int qq = 0; qq < 4; ++qq) cp[(size_t)qq * NC] = acc[i][j][qq];
    }
}

// ---------------------------------------------------------------------------
// gemm_ws (reg-staging, padded LDS): used for the fp32-A projection GEMMs.
// ---------------------------------------------------------------------------
template <bool SPLIT>
__global__ __launch_bounds__(256) void gemm_ws(
    const float* __restrict__ Af,
    const unsigned short* __restrict__ Bh, const unsigned short* __restrict__ Bl,
    float* __restrict__ C, int K, int ldA, int ldB, int S,
    long long sA, long long sB, long long sC) {
  const int z = blockIdx.z;
  const int batch = z / S, split = z - batch * S;
  Af += (long long)batch * sA;
  Bh += (long long)batch * sB;
  if constexpr (SPLIT) Bl += (long long)batch * sB;
  C += (long long)z * sC;

  const int gx = gridDim.x, gy = gridDim.y;
  const int nwg = gx * gy;
  const int wid = blockIdx.x + gx * blockIdx.y;
  const int q = nwg >> 3, r = nwg & 7;
  const int xcd = wid & 7, posn = wid >> 3;
  const int swz = (xcd < r ? xcd * (q + 1) : r * (q + 1) + (xcd - r) * q) + posn;
  const int mt = swz / gy;
  const int m0 = mt * 128, n0 = (swz - mt * gy) * 128;
  const int NC = gy << 7;

  const int kLen = K / S, k0base = split * kLen;
  constexpr int NBUF = SPLIT ? 4 : 2;
  __shared__ unsigned short lds[NBUF][128][40];

  const int t = threadIdx.x;
  const int wid4 = t >> 6, lane = t & 63;
  const int wr = wid4 >> 1, wc = wid4 & 1;
  const int lr = lane & 15, kq = lane >> 4;
  const int rowA8 = t >> 3, qdA = (t & 7) * 4;
  const int rowV = t >> 2, c8V = (t & 3) * 8;

  f32x4 rAf[4];
  u16x8 rBh[2], rBl[2];

  auto LOAD = [&](int kb) {
    #pragma unroll
    for (int a = 0; a < 4; ++a)
      rAf[a] = *(const f32x4*)(Af + (size_t)(m0 + rowA8 + 32 * a) * ldA + kb + qdA);
    #pragma unroll
    for (int a = 0; a < 2; ++a) {
      rBh[a] = *(const u16x8*)(Bh + (size_t)(n0 + rowV + 64 * a) * ldB + kb + c8V);
      if constexpr (SPLIT)
        rBl[a] = *(const u16x8*)(Bl + (size_t)(n0 + rowV + 64 * a) * ldB + kb + c8V);
    }
  };
  auto STORE = [&]() {
    #pragma unroll
    for (int a = 0; a < 4; ++a) {
      f32x4 v = rAf[a];
      u16x4 h = {f2bf(v[0]), f2bf(v[1]), f2bf(v[2]), f2bf(v[3])};
      *(u16x4*)&lds[0][rowA8 + 32 * a][qdA] = h;
      if constexpr (SPLIT) {
        u16x4 l = {f2bf(v[0] - bf2f(h[0])), f2bf(v[1] - bf2f(h[1])),
                   f2bf(v[2] - bf2f(h[2])), f2bf(v[3] - bf2f(h[3]))};
        *(u16x4*)&lds[2][rowA8 + 32 * a][qdA] = l;
      }
    }
    #pragma unroll
    for (int a = 0; a < 2; ++a) {
      *(u16x8*)&lds[1][rowV + 64 * a][c8V] = rBh[a];
      if constexpr (SPLIT) *(u16x8*)&lds[3][rowV + 64 * a][c8V] = rBl[a];
    }
  };

  f32x4 acc[4][4] = {};
  LOAD(k0base);
  for (int kk = 0; kk < kLen; kk += 32) {
    STORE();
    __syncthreads();
    if (kk + 32 < kLen) LOAD(k0base + kk + 32);

    bf16x8 ah[4], bh[4], al[4], bl[4];
    #pragma unroll
    for (int i = 0; i < 4; ++i) {
      ah[i] = __builtin_bit_cast(bf16x8, *(const u16x8*)&lds[0][wr * 64 + i * 16 + lr][kq * 8]);
      bh[i] = __builtin_bit_cast(bf16x8, *(const u16x8*)&lds[1][wc * 64 + i * 16 + lr][kq * 8]);
      if constexpr (SPLIT) {
        al[i] = __builtin_bit_cast(bf16x8, *(const u16x8*)&lds[2][wr * 64 + i * 16 + lr][kq * 8]);
        bl[i] = __builtin_bit_cast(bf16x8, *(const u16x8*)&lds[3][wc * 64 + i * 16 + lr][kq * 8]);
      }
    }
    #pragma unroll
    for (int i = 0; i < 4; ++i)
      #pragma unroll
      for (int j = 0; j < 4; ++j) {
        acc[i][j] = __builtin_amdgcn_mfma_f32_16x16x32_bf16(ah[i], bh[j], acc[i][j], 0, 0, 0);
        if constexpr (SPLIT) {
          acc[i][j] = __builtin_amdgcn_mfma_f32_16x16x32_bf16(ah[i], bl[j], acc[i][j], 0, 0, 0);
          acc[i][j] = __builtin_amdgcn_mfma_f32_16x16x32_bf16(al[i], bh[j], acc[i][j], 0, 0, 0);
        }
      }
    __syncthreads();
  }

  #pragma unroll
  for (int i = 0; i < 4; ++i)
    #pragma unroll
    for (int j = 0; j < 4; ++j) {
      float* cp = C + (size_t)(m0 + wr * 64 + i * 16 + kq * 4) * NC + n0 + wc * 64 + j * 16 + lr;
      #pragma unroll
      for (int qq = 0; qq < 4; ++qq) cp[(size_t)qq * NC] = acc[i][j][qq];
    }
}

// ---------------------------------------------------------------------------
// Output GEMM with fused combine: A[r][c] = (T4p 4-slab sum) +
// (T2p 4-slab sum)*einv_hval;  C = A @ W_o (split hi/lo). M=12288,N=256,K=256.
// ---------------------------------------------------------------------------
__global__ __launch_bounds__(256) void gemm_out(
    const float* __restrict__ T2p, const float* __restrict__ T4p,
    const float* __restrict__ hEi, const unsigned short* __restrict__ Bh,
    const unsigned short* __restrict__ Bl, float* __restrict__ C) {
  const int gx = gridDim.x, gy = gridDim.y;
  const int nwg = gx * gy;
  const int wid = blockIdx.x + gx * blockIdx.y;
  const int q = nwg >> 3, r = nwg & 7;
  const int xcd = wid & 7, posn = wid >> 3;
  const int swz = (xcd < r ? xcd * (q + 1) : r * (q + 1) + (xcd - r) * q) + posn;
  const int mt = swz / gy;
  const int m0 = mt * 128, n0 = (swz - mt * gy) * 128;

  __shared__ unsigned short lds[4][128][40];
  const int t = threadIdx.x;
  const int wid4 = t >> 6, lane = t & 63;
  const int wr = wid4 >> 1, wc = wid4 & 1;
  const int lr = lane & 15, kq = lane >> 4;
  const long long slab = 6144LL * 256;

  f32x4 acc[4][4] = {};

  for (int kb = 0; kb < 256; kb += 32) {
    #pragma unroll
    for (int a = 0; a < 4; ++a) {
      int idx = t + 256 * a;
      int row = idx >> 3, qd = (idx & 7) * 4;
      int rg = m0 + row;
      int b = rg >= 6144;
      int pos = rg - b * 6144;
      int ck = kb + qd;
      float s = hEi[((size_t)b * 8 + (ck >> 5)) * 6144 + pos];
      const float* b2 = T2p + ((long long)(b * 4) * 6144 + pos) * 256 + ck;
      const float* b4 = T4p + ((long long)(b * 4) * 6144 + pos) * 256 + ck;
      f32x4 t2 = (*(const f32x4*)b2 + *(const f32x4*)(b2 + slab)) +
                 (*(const f32x4*)(b2 + 2 * slab) + *(const f32x4*)(b2 + 3 * slab));
      f32x4 t4 = (*(const f32x4*)b4 + *(const f32x4*)(b4 + slab)) +
                 (*(const f32x4*)(b4 + 2 * slab) + *(const f32x4*)(b4 + 3 * slab));
      f32x4 v = t4 + t2 * s;
      u16x4 h = {f2bf(v[0]), f2bf(v[1]), f2bf(v[2]), f2bf(v[3])};
      *(u16x4*)&lds[0][row][qd] = h;
      u16x4 l = {f2bf(v[0] - bf2f(h[0])), f2bf(v[1] - bf2f(h[1])),
                 f2bf(v[2] - bf2f(h[2])), f2bf(v[3] - bf2f(h[3]))};
      *(u16x4*)&lds[2][row][qd] = l;
    }
    #pragma unroll
    for (int a = 0; a < 2; ++a) {
      int idx = t + 256 * a;
      int row = idx >> 2, c8 = (idx & 3) * 8;
      *(u16x8*)&lds[1][row][c8] = *(const u16x8*)(Bh + (size_t)(n0 + row) * 256 + kb + c8);
      *(u16x8*)&lds[3][row][c8] = *(const u16x8*)(Bl + (size_t)(n0 + row) * 256 + kb + c8);
    }
    __syncthreads();

    bf16x8 ah[4], bh[4], al[4], bl[4];
    #pragma unroll
    for (int i = 0; i < 4; ++i) {
      ah[i] = __builtin_bit_cast(bf16x8, *(const u16x8*)&lds[0][wr * 64 + i * 16 + lr][kq * 8]);
      bh[i] = __builtin_bit_cast(bf16x8, *(const u16x8*)&lds[1][wc * 64 + i * 16 + lr][kq * 8]);
      al[i] = __builtin_bit_cast(bf16x8, *(const u16x8*)&lds[2][wr * 64 + i * 16 + lr][kq * 8]);
      bl[i] = __builtin_bit_cast(bf16x8, *(const u16x8*)&lds[3][wc * 64 + i * 16 + lr][kq * 8]);
    }
    #pragma unroll
    for (int i = 0; i < 4; ++i)
      #pragma unroll
      for (int j = 0; j < 4; ++j) {
        acc[i][j] = __builtin_amdgcn_mfma_f32_16x16x32_bf16(ah[i], bh[j], acc[i][j], 0, 0, 0);
        acc[i][j] = __builtin_amdgcn_mfma_f32_16x16x32_bf16(ah[i], bl[j], acc[i][j], 0, 0, 0);
        acc[i][j] = __builtin_amdgcn_mfma_f32_16x16x32_bf16(al[i], bh[j], acc[i][j], 0, 0, 0);
      }
    __syncthreads();
  }

  #pragma unroll
  for (int i = 0; i < 4; ++i)
    #pragma unroll
    for (int j = 0; j < 4; ++j) {
      float* cp = C + (size_t)(m0 + wr * 64 + i * 16 + kq * 4) * 256 + n0 + wc * 64 + j * 16 + lr;
      #pragma unroll
      for (int qq = 0; qq < 4; ++qq) cp[(size_t)qq * 256] = acc[i][j][qq];
    }
}

// ---------------------------------------------------------------------------
// d1 pass: reads d1 [2][4096][6144] fp32; writes d1N_hi (natural bf16) and
// d1T_hi (transposed bf16 [2][6144][4096]).
// ---------------------------------------------------------------------------
__global__ __launch_bounds__(256) void xpose_d1(
    const float* __restrict__ d1, unsigned short* __restrict__ d1T,
    unsigned short* __restrict__ d1N) {
  __shared__ unsigned short thi[64][72];
  const int b = blockIdx.z;
  const int r0 = blockIdx.x * 64, c0 = blockIdx.y * 64;
  const int t = threadIdx.x;
  #pragma unroll
  for (int a = 0; a < 4; ++a) {
    int idx = t + 256 * a;
    int tr = idx >> 4, tc = (idx & 15) * 4;
    f32x4 v = *(const f32x4*)(d1 + ((size_t)b * 4096 + r0 + tr) * 6144 + c0 + tc);
    u16x4 hh = {f2bf(v[0]), f2bf(v[1]), f2bf(v[2]), f2bf(v[3])};
    *(u16x4*)&thi[tr][tc] = hh;
    *(u16x4*)(d1N + ((size_t)b * 4096 + r0 + tr) * 6144 + c0 + tc) = hh;
  }
  __syncthreads();
  #pragma unroll
  for (int a = 0; a < 2; ++a) {
    int idx = t + 256 * a;
    int orow = idx >> 3, oc = (idx & 7) * 8;
    u16x8 vh;
    #pragma unroll
    for (int j = 0; j < 8; ++j) vh[j] = thi[oc + j][orow];
    *(u16x8*)(d1T + ((size_t)b * 6144 + c0 + orow) * 4096 + r0 + oc) = vh;
  }
}

// ---------------------------------------------------------------------------
// d0 pass: reads d0 [2][6144][2048] fp32; writes d0N hi/lo (natural) and
// d0T hi/lo (transposed [2][2048][6144]).
// ---------------------------------------------------------------------------
__global__ __launch_bounds__(256) void xpose_d0(
    const float* __restrict__ d0, unsigned short* __restrict__ d0T_hi,
    unsigned short* __restrict__ d0T_lo, unsigned short* __restrict__ d0N_hi,
    unsigned short* __restrict__ d0N_lo) {
  __shared__ unsigned short thi[64][72], tlo[64][72];
  const int b = blockIdx.z;
  const int r0 = blockIdx.x * 64, c0 = blockIdx.y * 64;
  const int t = threadIdx.x;
  #pragma unroll
  for (int a = 0; a < 4; ++a) {
    int idx = t + 256 * a;
    int tr = idx >> 4, tc = (idx & 15) * 4;
    size_t off = ((size_t)b * 6144 + r0 + tr) * 2048 + c0 + tc;
    f32x4 v = *(const f32x4*)(d0 + off);
    u16x4 hh = {f2bf(v[0]), f2bf(v[1]), f2bf(v[2]), f2bf(v[3])};
    u16x4 ll = {f2bf(v[0] - bf2f(hh[0])), f2bf(v[1] - bf2f(hh[1])),
                f2bf(v[2] - bf2f(hh[2])), f2bf(v[3] - bf2f(hh[3]))};
    *(u16x4*)&thi[tr][tc] = hh;
    *(u16x4*)&tlo[tr][tc] = ll;
    *(u16x4*)(d0N_hi + off) = hh;
    *(u16x4*)(d0N_lo + off) = ll;
  }
  __syncthreads();
  #pragma unroll
  for (int a = 0; a < 2; ++a) {
    int idx = t + 256 * a;
    int orow = idx >> 3, oc = (idx & 7) * 8;
    u16x8 vh, vl;
    #pragma unroll
    for (int j = 0; j < 8; ++j) { vh[j] = thi[oc + j][orow]; vl[j] = tlo[oc + j][orow]; }
    size_t o = ((size_t)b * 2048 + c0 + orow) * 6144 + r0 + oc;
    *(u16x8*)(d0T_hi + o) = vh;
    *(u16x8*)(d0T_lo + o) = vl;
  }
}

// Batched 256x256 weight transposes (z selects).
struct WTab {
  const float* s[8];
  unsigned short* h[8];
  unsigned short* l[8];
};
__global__ __launch_bounds__(256) void wxpose(WTab tab) {
  __shared__ unsigned short thi[64][72], tlo[64][72];
  const int w = blockIdx.z;
  const float* src = tab.s[w];
  unsigned short* oh = tab.h[w];
  unsigned short* ol = tab.l[w];
  const int r0 = blockIdx.x * 64, c0 = blockIdx.y * 64;
  const int t = threadIdx.x;
  #pragma unroll
  for (int a = 0; a < 4; ++a) {
    int idx = t + 256 * a;
    int tr = idx >> 4, tc = (idx & 15) * 4;
    f32x4 v = *(const f32x4*)(src + (size_t)(r0 + tr) * 256 + c0 + tc);
    u16x4 hh = {f2bf(v[0]), f2bf(v[1]), f2bf(v[2]), f2bf(v[3])};
    *(u16x4*)&thi[tr][tc] = hh;
    if (ol) {
      u16x4 ll = {f2bf(v[0] - bf2f(hh[0])), f2bf(v[1] - bf2f(hh[1])),
                  f2bf(v[2] - bf2f(hh[2])), f2bf(v[3] - bf2f(hh[3]))};
      *(u16x4*)&tlo[tr][tc] = ll;
    }
  }
  __syncthreads();
  #pragma unroll
  for (int a = 0; a < 2; ++a) {
    int idx = t + 256 * a;
    int orow = idx >> 3, oc = (idx & 7) * 8;
    u16x8 vh;
    #pragma unroll
    for (int j = 0; j < 8; ++j) vh[j] = thi[oc + j][orow];
    *(u16x8*)(oh + (size_t)(c0 + orow) * 256 + r0 + oc) = vh;
    if (ol) {
      u16x8 vl;
      #pragma unroll
      for (int j = 0; j < 8; ++j) vl[j] = tlo[oc + j][orow];
      *(u16x8*)(ol + (size_t)(c0 + orow) * 256 + r0 + oc) = vl;
    }
  }
}

// ---------------------------------------------------------------------------
// Fused eVT (unscaled bf16) + Y0T (scaled hi/lo) from P1 cols 512..767
// (row stride 1280).
// ---------------------------------------------------------------------------
__global__ __launch_bounds__(256) void xpose_ev(
    const float* __restrict__ P1, unsigned short* __restrict__ eVT,
    unsigned short* __restrict__ yhi, unsigned short* __restrict__ ylo,
    const float* __restrict__ hE) {
  __shared__ unsigned short te[64][72], th[64][72], tl[64][72];
  const int b = blockIdx.z;
  const int r0 = blockIdx.x * 64, c0 = blockIdx.y * 64;
  const int t = threadIdx.x;
  #pragma unroll
  for (int a = 0; a < 4; ++a) {
    int idx = t + 256 * a;
    int tr = idx >> 4, tc = (idx & 15) * 4;
    f32x4 v = *(const f32x4*)(P1 + ((size_t)b * 6144 + r0 + tr) * 1280 + 512 + c0 + tc);
    u16x4 eh = {f2bf(v[0]), f2bf(v[1]), f2bf(v[2]), f2bf(v[3])};
    *(u16x4*)&te[tr][tc] = eh;
    float s = hE[((size_t)b * 8 + ((c0 + tc) >> 5)) * 6144 + r0 + tr];
    f32x4 y = v * s;
    u16x4 hh = {f2bf(y[0]), f2bf(y[1]), f2bf(y[2]), f2bf(y[3])};
    *(u16x4*)&th[tr][tc] = hh;
    u16x4 ll = {f2bf(y[0] - bf2f(hh[0])), f2bf(y[1] - bf2f(hh[1])),
                f2bf(y[2] - bf2f(hh[2])), f2bf(y[3] - bf2f(hh[3]))};
    *(u16x4*)&tl[tr][tc] = ll;
  }
  __syncthreads();
  #pragma unroll
  for (int a = 0; a < 2; ++a) {
    int idx = t + 256 * a;
    int orow = idx >> 3, oc = (idx & 7) * 8;
    u16x8 ve, vh, vl;
    #pragma unroll
    for (int j = 0; j < 8; ++j) {
      ve[j] = te[oc + j][orow];
      vh[j] = th[oc + j][orow];
      vl[j] = tl[oc + j][orow];
    }
    size_t o = ((size_t)b * 256 + c0 + orow) * 6144 + r0 + oc;
    *(u16x8*)(eVT + o) = ve;
    *(u16x8*)(yhi + o) = vh;
    *(u16x8*)(ylo + o) = vl;
  }
}

// ---------------------------------------------------------------------------
// rsc_cvt: in fp32 [2][S][R][P] -> out bf16 hi(+lo) [2][R][P], sum S slabs,
// scale by h[b][row>>5][col].
// ---------------------------------------------------------------------------
__global__ void rsc_cvt(const float* __restrict__ in,
                        unsigned short* __restrict__ out_hi,
                        unsigned short* __restrict__ out_lo,
                        const float* __restrict__ h, int S, int R, int P) {
  const long long qP = P >> 2;
  const long long nq = 2LL * R * qP;
  long long i = (long long)blockIdx.x * blockDim.x + threadIdx.x;
  const long long stride = (long long)gridDim.x * blockDim.x;
  for (; i < nq; i += stride) {
    long long b = i / (R * qP);
    long long rem = i - b * (R * qP);
    int row = (int)(rem / qP);
    long long qc = rem - (long long)row * qP;
    const f32x4* base = (const f32x4*)in + ((b * S) * R + row) * qP + qc;
    f32x4 v = base[0];
    for (int s = 1; s < S; ++s) v += base[(long long)s * R * qP];
    v *= *(const f32x4*)(h + ((size_t)b * 8 + (row >> 5)) * P + (qc << 2));
    u16x4 hh = {f2bf(v[0]), f2bf(v[1]), f2bf(v[2]), f2bf(v[3])};
    ((u16x4*)out_hi)[i] = hh;
    if (out_lo) {
      u16x4 ll = {f2bf(v[0] - bf2f(hh[0])), f2bf(v[1] - bf2f(hh[1])),
                  f2bf(v[2] - bf2f(hh[2])), f2bf(v[3] - bf2f(hh[3]))};
      ((u16x4*)out_lo)[i] = ll;
    }
  }
}

// ---------------------------------------------------------------------------
// v-pair hval, numpy-fp32-exact (validated R3). 8 rows per block.
// ---------------------------------------------------------------------------
__global__ __launch_bounds__(256) void vproj_hval_np(
    const float* __restrict__ X, const float* __restrict__ Wq,
    const float* __restrict__ Wk, float* __restrict__ hout, int P) {
  __shared__ float sx[8][256], sq[8][256], sk[8][256];
  const int r0 = blockIdx.x * 8;
  const int j = threadIdx.x;
  #pragma unroll
  for (int r = 0; r < 8; ++r) sx[r][j] = X[(size_t)(r0 + r) * 256 + j];
  __syncthreads();
  float qa[8] = {}, ka[8] = {};
  for (int i = 0; i < 256; ++i) {
    float wq = Wq[i * 256 + j], wk = Wk[i * 256 + j];
    #pragma unroll
    for (int r = 0; r < 8; ++r) {
      qa[r] = __fmaf_rn(sx[r][i], wq, qa[r]);
      ka[r] = __fmaf_rn(sx[r][i], wk, ka[r]);
    }
  }
  #pragma unroll
  for (int r = 0; r < 8; ++r) { sq[r][j] = qa[r]; sk[r][j] = ka[r]; }
  __syncthreads();
  if (j < 64) {
    const int r = j >> 3, head = j & 7;
    const float* qq = &sq[r][head * 32];
    const float* kk = &sk[r][head * 32];
    float s0 = 0.0f, s1 = 0.0f, s2 = 0.0f, s3 = 0.0f;
    #pragma unroll 1
    for (int d = 0; d < 32; d += 4) {
      s0 = __fadd_rn(s0, __fmul_rn(qq[d + 0], kk[d + 0]));
      s1 = __fadd_rn(s1, __fmul_rn(qq[d + 1], kk[d + 1]));
      s2 = __fadd_rn(s2, __fmul_rn(qq[d + 2], kk[d + 2]));
      s3 = __fadd_rn(s3, __fmul_rn(qq[d + 3], kk[d + 3]));
    }
    float p = __fadd_rn(__fadd_rn(s0, s2), __fadd_rn(s1, s3));
    float hval = __fdiv_rn(p, sqrtf(32.0f));
    float inv = __fdiv_rn(1.0f, __fadd_rn(hval, 1e-6f));
    const int row = r0 + r;
    const int b = row / P, pos = row - b * P;
    hout[((size_t)b * 8 + head) * P + pos] = inv;
  }
}

// e_hval (cols 0/256) and einv_hval (cols 768/1024) from P1 [12288][1280].
__global__ __launch_bounds__(256) void dot2_hval(
    const float* __restrict__ P1, float* __restrict__ hE,
    float* __restrict__ hEi) {
  const int wv = threadIdx.x >> 6, lane = threadIdx.x & 63;
  const int row = blockIdx.x * 4 + wv;
  const float* base = P1 + (size_t)row * 1280 + lane * 4;
  f32x4 q = *(const f32x4*)(base);
  f32x4 k = *(const f32x4*)(base + 256);
  float p = q[0] * k[0] + q[1] * k[1] + q[2] * k[2] + q[3] * k[3];
  p += __shfl_xor(p, 1); p += __shfl_xor(p, 2); p += __shfl_xor(p, 4);
  f32x4 q2 = *(const f32x4*)(base + 768);
  f32x4 k2 = *(const f32x4*)(base + 1024);
  float p2 = q2[0] * k2[0] + q2[1] * k2[1] + q2[2] * k2[2] + q2[3] * k2[3];
  p2 += __shfl_xor(p2, 1); p2 += __shfl_xor(p2, 2); p2 += __shfl_xor(p2, 4);
  if ((lane & 7) == 0) {
    const int head = lane >> 3;
    const int b = row / 6144, pos = row % 6144;
    hE[((size_t)b * 8 + head) * 6144 + pos] = p * 0.17677669529663687f;
    hEi[((size_t)b * 8 + head) * 6144 + pos] = p2 * 0.17677669529663687f;
  }
}

// hval = rowwise per-head dot of fp32 Q,K (ld = row stride). One wave/row.
__global__ __launch_bounds__(256) void dot_hval(
    const float* __restrict__ Q, const float* __restrict__ K,
    float* __restrict__ hout, int P, int ld) {
  const int wv = threadIdx.x >> 6, lane = threadIdx.x & 63;
  const int row = blockIdx.x * 4 + wv;
  f32x4 q = *(const f32x4*)(Q + (size_t)row * ld + lane * 4);
  f32x4 k = *(const f32x4*)(K + (size_t)row * ld + lane * 4);
  float p = q[0] * k[0] + q[1] * k[1] + q[2] * k[2] + q[3] * k[3];
  p += __shfl_xor(p, 1); p += __shfl_xor(p, 2); p += __shfl_xor(p, 4);
  if ((lane & 7) == 0) {
    const int head = lane >> 3;
    const int b = row / P, pos = row % P;
    hout[((size_t)b * 8 + head) * P + pos] = p * 0.17677669529663687f;
  }
}

// ---------------------------------------------------------------------------
extern "C" void kernel_launch(void* const* d_in, const int* in_sizes, int n_in,
                              void* d_out, int out_size, void* d_ws, size_t ws_size,
                              hipStream_t stream) {
  const float* x_v = (const float*)d_in[0];
  const float* x_e = (const float*)d_in[1];
  const float* x_f = (const float*)d_in[2];
  const float* d0  = (const float*)d_in[3];   // (2, 6144, 2048)
  const float* d1  = (const float*)d_in[4];   // (2, 4096, 6144)
  const float* W_vq = (const float*)d_in[5];
  const float* W_vk = (const float*)d_in[6];
  float* out = (float*)d_out;

  const int NV = 2048, ME = 6144, KF = 4096;
  const unsigned short* NUS = nullptr;

  char* ws = (char*)d_ws;
  size_t o = 0;
  auto alloc = [&](size_t bytes) { size_t r = o; o = (o + bytes + 255) & ~255ULL; return r; };

  unsigned short* Wcat5_hi = (unsigned short*)(ws + alloc(1280 * 256 * 2));
  unsigned short* Wcat5_lo = (unsigned short*)(ws + alloc(1280 * 256 * 2));
  unsigned short* W3_hi = (unsigned short*)(ws + alloc(512 * 256 * 2));
  unsigned short* Wo_hi = (unsigned short*)(ws + alloc(256 * 256 * 2));
  unsigned short* Wo_lo = (unsigned short*)(ws + alloc(256 * 256 * 2));
  float* pHvE  = (float*)(ws + alloc(2 * 8 * ME * 4));
  float* pHvEi = (float*)(ws + alloc(2 * 8 * ME * 4));
  float* pHvF  = (float*)(ws + alloc(2 * 8 * KF * 4));
  float* pHvV  = (float*)(ws + alloc(2 * 8 * NV * 4));
  unsigned short* d1T_hi = (unsigned short*)(ws + alloc((size_t)2 * ME * KF * 2));   // [2][6144][4096]
  unsigned short* d1N_hi = (unsigned short*)(ws + alloc((size_t)2 * KF * ME * 2));   // [2][4096][6144]
  unsigned short* d0T_hi = (unsigned short*)(ws + alloc((size_t)2 * NV * ME * 2));   // [2][2048][6144]
  unsigned short* d0T_lo = (unsigned short*)(ws + alloc((size_t)2 * NV * ME * 2));
  unsigned short* d0N_hi = (unsigned short*)(ws + alloc((size_t)2 * ME * NV * 2));   // [2][6144][2048]
  unsigned short* d0N_lo = (unsigned short*)(ws + alloc((size_t)2 * ME * NV * 2));
  unsigned short* eVT_hi = (unsigned short*)(ws + alloc((size_t)2 * 256 * ME * 2));  // [2][256][6144]
  unsigned short* Y0T_hi = (unsigned short*)(ws + alloc((size_t)2 * 256 * ME * 2));
  unsigned short* Y0T_lo = (unsigned short*)(ws + alloc((size_t)2 * 256 * ME * 2));
  unsigned short* T1sT_hi = (unsigned short*)(ws + alloc((size_t)2 * 256 * KF * 2)); // [2][256][4096]
  unsigned short* T3sT_hi = (unsigned short*)(ws + alloc((size_t)2 * 256 * NV * 2)); // [2][256][2048]
  unsigned short* T3sT_lo = (unsigned short*)(ws + alloc((size_t)2 * 256 * NV * 2));
  float* pP1 = (float*)(ws + alloc((size_t)12288 * 1280 * 4));   // e projections (N=1280)
  float* pP3 = (float*)(ws + alloc((size_t)8192 * 512 * 4));     // f projections
  float* pTp1 = (float*)(ws + alloc((size_t)2 * 6 * 256 * KF * 4));   // T1^T slabs
  float* pTp3 = (float*)(ws + alloc((size_t)2 * 12 * 256 * NV * 4));  // T3^T slabs
  float* pT2p = (float*)(ws + alloc((size_t)2 * 4 * ME * 256 * 4));
  float* pT4p = (float*)(ws + alloc((size_t)2 * 4 * ME * 256 * 4));

  dim3 blk(256);

  // --- batched weight transposes -> bf16 [n][k] ---
  WTab tab;
  tab.s[0] = (const float*)d_in[7];  tab.h[0] = Wcat5_hi;            tab.l[0] = Wcat5_lo;            // eq
  tab.s[1] = (const float*)d_in[8];  tab.h[1] = Wcat5_hi + 65536;    tab.l[1] = Wcat5_lo + 65536;    // ek
  tab.s[2] = (const float*)d_in[11]; tab.h[2] = Wcat5_hi + 131072;   tab.l[2] = Wcat5_lo + 131072;   // ev
  tab.s[3] = (const float*)d_in[9];  tab.h[3] = Wcat5_hi + 196608;   tab.l[3] = Wcat5_lo + 196608;   // einvq
  tab.s[4] = (const float*)d_in[10]; tab.h[4] = Wcat5_hi + 262144;   tab.l[4] = Wcat5_lo + 262144;   // einvk
  tab.s[5] = (const float*)d_in[12]; tab.h[5] = W3_hi;               tab.l[5] = nullptr;             // fq
  tab.s[6] = (const float*)d_in[13]; tab.h[6] = W3_hi + 65536;       tab.l[6] = nullptr;             // fk
  tab.s[7] = (const float*)d_in[14]; tab.h[7] = Wo_hi;               tab.l[7] = Wo_lo;               // o
  wxpose<<<dim3(4, 4, 8), blk, 0, stream>>>(tab);

  // --- d-matrix conversions (transposed + natural bf16, one read each) ---
  xpose_d1<<<dim3(64, 96, 2), blk, 0, stream>>>(d1, d1T_hi, d1N_hi);
  xpose_d0<<<dim3(96, 32, 2), blk, 0, stream>>>(d0, d0T_hi, d0T_lo, d0N_hi, d0N_lo);

  // --- v hval (np-fp32 exact) ---
  vproj_hval_np<<<512, blk, 0, stream>>>(x_v, W_vq, W_vk, pHvV, NV);

  // --- projections: P1 = x_e @ [eq|ek|ev|einvq|einvk] (split), P3 = x_f @ [fq|fk] ---
  gemm_ws<true><<<dim3(96, 10, 1), blk, 0, stream>>>(
      x_e, Wcat5_hi, Wcat5_lo, pP1, 256, 256, 256, 1, 0, 0, 0);
  dot2_hval<<<3072, blk, 0, stream>>>(pP1, pHvE, pHvEi);
  xpose_ev<<<dim3(96, 4, 2), blk, 0, stream>>>(pP1, eVT_hi, Y0T_hi, Y0T_lo, pHvE);
  gemm_ws<false><<<dim3(64, 4, 1), blk, 0, stream>>>(
      x_f, W3_hi, NUS, pP3, 256, 256, 256, 1, 0, 0, 0);
  dot_hval<<<2048, blk, 0, stream>>>(pP3, pP3 + 256, pHvF, KF, 512);

  // --- T1 || T3 (independent big GEMMs, tail overlap) ---
  // T1^T = eVT @ d1N (plain), S=6 -> [2][6][256][4096]
  gemm_bb<false, true><<<dim3(2, 32, 12), blk, 0, stream>>>(
      eVT_hi, NUS, d1N_hi, NUS, pTp1, ME, ME, ME, 6,
      256LL * ME, (long long)KF * ME, 256LL * KF);
  // T3^T = Y0T @ d0T (split), S=12 -> [2][12][256][2048]
  gemm_bb<true, true><<<dim3(2, 16, 24), blk, 0, stream>>>(
      Y0T_hi, Y0T_lo, d0T_hi, d0T_lo, pTp3, ME, ME, ME, 12,
      256LL * ME, (long long)NV * ME, 256LL * NV);

  // --- reductions + scale + cvt ---
  rsc_cvt<<<2048, blk, 0, stream>>>(pTp1, T1sT_hi, nullptr, pHvF, 6, 256, KF);
  rsc_cvt<<<1024, blk, 0, stream>>>(pTp3, T3sT_hi, T3sT_lo, pHvV, 12, 256, NV);

  // --- T2 || T4 ---
  // T2 = d1T @ T1s (plain), S=4 -> [2][4][6144][256]
  gemm_bb<false, false><<<dim3(48, 2, 8), blk, 0, stream>>>(
      d1T_hi, NUS, T1sT_hi, NUS, pT2p, KF, KF, KF, 4,
      (long long)ME * KF, 256LL * KF, (long long)ME * 256);
  // T4 = d0N @ T3s (split), S=4 -> [2][4][6144][256]
  gemm_bb<true, false><<<dim3(48, 2, 8), blk, 0, stream>>>(
      d0N_hi, d0N_lo, T3sT_hi, T3sT_lo, pT4p, NV, NV, NV, 4,
      (long long)ME * NV, 256LL * NV, (long long)ME * 256);

  // --- fused combine + output projection ---
  gemm_out<<<dim3(96, 2, 1), blk, 0, stream>>>(pT2p, pT4p, pHvEi, Wo_hi, Wo_lo, out);
}

// Round 9
// 501.422 us; speedup vs baseline: 1.1379x; 1.1379x over previous
//
#include <hip/hip_runtime.h>
#include <hip/hip_bf16.h>
#include <cstdint>
#include <cstddef>

// ---------------------------------------------------------------------------
// MeshMultiHeadHodgeLaplaceAttention  (b=2, n=2048, m=6144, k=4096, D=256, H=8)
//
//   up:   T1 = d_1 @ eV ; *f_hval ; T2 = d_1^T @ T1s ; (*einv_hval in combine)
//   down: Y0 = eV*e_hval ; T3 = d_0^T @ Y0 ; *1/(v_hval+eps) ; T4 = d_0 @ T3s
//   out = (T2*einv_hval + T4) @ W_o
//
// Precision (validated R3-R8, absmax=256): v_hval replicates numpy fp32
// bit-exactly; amplified chain split-bf16 (hi/lo, 3 MFMA); up branch plain.
//
// R9: revert R8's global_load_lds experiment (regressed: killed the reg-
// prefetch overlap). Restore R7 reg-staging GEMM. New: fuse all independent
// prep work (8 weight transposes + d1 pass + d0 pass + vproj) into ONE
// mega-kernel so vproj's VALU work hides under transpose streaming; merge
// the two rsc_cvt launches. Identical per-element arithmetic.
// ---------------------------------------------------------------------------

typedef __attribute__((ext_vector_type(4))) float f32x4;
typedef __attribute__((ext_vector_type(4))) unsigned short u16x4;
typedef __attribute__((ext_vector_type(8))) unsigned short u16x8;
typedef __attribute__((ext_vector_type(8))) __bf16 bf16x8;

static __device__ __forceinline__ unsigned short f2bf(float f) {
  uint32_t u = __builtin_bit_cast(uint32_t, f);
  uint32_t r = (u + 0x7FFFu + ((u >> 16) & 1u)) >> 16;  // RNE
  return (unsigned short)r;
}
static __device__ __forceinline__ float bf2f(unsigned short h) {
  return __builtin_bit_cast(float, (uint32_t)h << 16);
}

// ---------------------------------------------------------------------------
// gemm_ws (R7): C[M x NC] = A[M x K] * B[N x K]^T-layout, NC = gridDim.y*128.
// A: fp32 [M][K] cvt-in-staging (!ABF) or bf16 hi(/lo) [M][K] (ABF).
// B: bf16 hi(/lo) [N][K]. Split-K via blockIdx.z = batch*S + split.
// Register-prefetch: next tile's global loads issued under current MFMA.
// ---------------------------------------------------------------------------
template <bool ABF, bool SPLIT, bool XFAST>
__global__ __launch_bounds__(256) void gemm_ws(
    const float* __restrict__ Af, const unsigned short* __restrict__ Ah,
    const unsigned short* __restrict__ Al,
    const unsigned short* __restrict__ Bh, const unsigned short* __restrict__ Bl,
    float* __restrict__ C, int K, int ldA, int ldB, int S,
    long long sA, long long sB, long long sC) {
  const int z = blockIdx.z;
  const int batch = z / S, split = z - batch * S;
  if constexpr (ABF) {
    Ah += (long long)batch * sA;
    if constexpr (SPLIT) Al += (long long)batch * sA;
  } else {
    Af += (long long)batch * sA;
  }
  Bh += (long long)batch * sB;
  if constexpr (SPLIT) Bl += (long long)batch * sB;
  C += (long long)z * sC;

  const int gx = gridDim.x, gy = gridDim.y;
  const int nwg = gx * gy;
  const int wid = blockIdx.x + gx * blockIdx.y;
  const int q = nwg >> 3, r = nwg & 7;
  const int xcd = wid & 7, posn = wid >> 3;
  const int swz = (xcd < r ? xcd * (q + 1) : r * (q + 1) + (xcd - r) * q) + posn;
  int mt, nt;
  if constexpr (XFAST) { mt = swz % gx; nt = swz / gx; }
  else                 { mt = swz / gy; nt = swz - mt * gy; }
  const int m0 = mt * 128, n0 = nt * 128;
  const int NC = gy << 7;

  const int kLen = K / S, k0base = split * kLen;
  constexpr int NBUF = SPLIT ? 4 : 2;
  __shared__ unsigned short lds[NBUF][128][40];

  const int t = threadIdx.x;
  const int wid4 = t >> 6, lane = t & 63;
  const int wr = wid4 >> 1, wc = wid4 & 1;
  const int lr = lane & 15, kq = lane >> 4;
  const int rowA8 = t >> 3, qdA = (t & 7) * 4;
  const int rowV = t >> 2, c8V = (t & 3) * 8;

  f32x4 rAf[4];
  u16x8 rAh[2], rAl[2], rBh[2], rBl[2];

  auto LOAD = [&](int kb) {
    if constexpr (!ABF) {
      #pragma unroll
      for (int a = 0; a < 4; ++a)
        rAf[a] = *(const f32x4*)(Af + (size_t)(m0 + rowA8 + 32 * a) * ldA + kb + qdA);
    } else {
      #pragma unroll
      for (int a = 0; a < 2; ++a) {
        rAh[a] = *(const u16x8*)(Ah + (size_t)(m0 + rowV + 64 * a) * ldA + kb + c8V);
        if constexpr (SPLIT)
          rAl[a] = *(const u16x8*)(Al + (size_t)(m0 + rowV + 64 * a) * ldA + kb + c8V);
      }
    }
    #pragma unroll
    for (int a = 0; a < 2; ++a) {
      rBh[a] = *(const u16x8*)(Bh + (size_t)(n0 + rowV + 64 * a) * ldB + kb + c8V);
      if constexpr (SPLIT)
        rBl[a] = *(const u16x8*)(Bl + (size_t)(n0 + rowV + 64 * a) * ldB + kb + c8V);
    }
  };
  auto STORE = [&]() {
    if constexpr (!ABF) {
      #pragma unroll
      for (int a = 0; a < 4; ++a) {
        f32x4 v = rAf[a];
        u16x4 h = {f2bf(v[0]), f2bf(v[1]), f2bf(v[2]), f2bf(v[3])};
        *(u16x4*)&lds[0][rowA8 + 32 * a][qdA] = h;
        if constexpr (SPLIT) {
          u16x4 l = {f2bf(v[0] - bf2f(h[0])), f2bf(v[1] - bf2f(h[1])),
                     f2bf(v[2] - bf2f(h[2])), f2bf(v[3] - bf2f(h[3]))};
          *(u16x4*)&lds[2][rowA8 + 32 * a][qdA] = l;
        }
      }
    } else {
      #pragma unroll
      for (int a = 0; a < 2; ++a) {
        *(u16x8*)&lds[0][rowV + 64 * a][c8V] = rAh[a];
        if constexpr (SPLIT) *(u16x8*)&lds[2][rowV + 64 * a][c8V] = rAl[a];
      }
    }
    #pragma unroll
    for (int a = 0; a < 2; ++a) {
      *(u16x8*)&lds[1][rowV + 64 * a][c8V] = rBh[a];
      if constexpr (SPLIT) *(u16x8*)&lds[3][rowV + 64 * a][c8V] = rBl[a];
    }
  };

  f32x4 acc[4][4] = {};
  LOAD(k0base);
  for (int kk = 0; kk < kLen; kk += 32) {
    STORE();
    __syncthreads();
    if (kk + 32 < kLen) LOAD(k0base + kk + 32);

    bf16x8 ah[4], bh[4], al[4], bl[4];
    #pragma unroll
    for (int i = 0; i < 4; ++i) {
      ah[i] = __builtin_bit_cast(bf16x8, *(const u16x8*)&lds[0][wr * 64 + i * 16 + lr][kq * 8]);
      bh[i] = __builtin_bit_cast(bf16x8, *(const u16x8*)&lds[1][wc * 64 + i * 16 + lr][kq * 8]);
      if constexpr (SPLIT) {
        al[i] = __builtin_bit_cast(bf16x8, *(const u16x8*)&lds[2][wr * 64 + i * 16 + lr][kq * 8]);
        bl[i] = __builtin_bit_cast(bf16x8, *(const u16x8*)&lds[3][wc * 64 + i * 16 + lr][kq * 8]);
      }
    }
    #pragma unroll
    for (int i = 0; i < 4; ++i)
      #pragma unroll
      for (int j = 0; j < 4; ++j) {
        acc[i][j] = __builtin_amdgcn_mfma_f32_16x16x32_bf16(ah[i], bh[j], acc[i][j], 0, 0, 0);
        if constexpr (SPLIT) {
          acc[i][j] = __builtin_amdgcn_mfma_f32_16x16x32_bf16(ah[i], bl[j], acc[i][j], 0, 0, 0);
          acc[i][j] = __builtin_amdgcn_mfma_f32_16x16x32_bf16(al[i], bh[j], acc[i][j], 0, 0, 0);
        }
      }
    __syncthreads();
  }

  #pragma unroll
  for (int i = 0; i < 4; ++i)
    #pragma unroll
    for (int j = 0; j < 4; ++j) {
      float* cp = C + (size_t)(m0 + wr * 64 + i * 16 + kq * 4) * NC + n0 + wc * 64 + j * 16 + lr;
      #pragma unroll
      for (int qq = 0; qq < 4; ++qq) cp[(size_t)qq * NC] = acc[i][j][qq];
    }
}

// ---------------------------------------------------------------------------
// Output GEMM with fused combine (R7).
// ---------------------------------------------------------------------------
__global__ __launch_bounds__(256) void gemm_out(
    const float* __restrict__ T2p, const float* __restrict__ T4p,
    const float* __restrict__ hEi, const unsigned short* __restrict__ Bh,
    const unsigned short* __restrict__ Bl, float* __restrict__ C) {
  const int gx = gridDim.x, gy = gridDim.y;
  const int nwg = gx * gy;
  const int wid = blockIdx.x + gx * blockIdx.y;
  const int q = nwg >> 3, r = nwg & 7;
  const int xcd = wid & 7, posn = wid >> 3;
  const int swz = (xcd < r ? xcd * (q + 1) : r * (q + 1) + (xcd - r) * q) + posn;
  const int mt = swz / gy;
  const int m0 = mt * 128, n0 = (swz - mt * gy) * 128;

  __shared__ unsigned short lds[4][128][40];
  const int t = threadIdx.x;
  const int wid4 = t >> 6, lane = t & 63;
  const int wr = wid4 >> 1, wc = wid4 & 1;
  const int lr = lane & 15, kq = lane >> 4;
  const long long slab = 6144LL * 256;

  f32x4 acc[4][4] = {};

  for (int kb = 0; kb < 256; kb += 32) {
    #pragma unroll
    for (int a = 0; a < 4; ++a) {
      int idx = t + 256 * a;
      int row = idx >> 3, qd = (idx & 7) * 4;
      int rg = m0 + row;
      int b = rg >= 6144;
      int pos = rg - b * 6144;
      int ck = kb + qd;
      float s = hEi[((size_t)b * 8 + (ck >> 5)) * 6144 + pos];
      const float* b2 = T2p + ((long long)(b * 4) * 6144 + pos) * 256 + ck;
      const float* b4 = T4p + ((long long)(b * 4) * 6144 + pos) * 256 + ck;
      f32x4 t2 = (*(const f32x4*)b2 + *(const f32x4*)(b2 + slab)) +
                 (*(const f32x4*)(b2 + 2 * slab) + *(const f32x4*)(b2 + 3 * slab));
      f32x4 t4 = (*(const f32x4*)b4 + *(const f32x4*)(b4 + slab)) +
                 (*(const f32x4*)(b4 + 2 * slab) + *(const f32x4*)(b4 + 3 * slab));
      f32x4 v = t4 + t2 * s;
      u16x4 h = {f2bf(v[0]), f2bf(v[1]), f2bf(v[2]), f2bf(v[3])};
      *(u16x4*)&lds[0][row][qd] = h;
      u16x4 l = {f2bf(v[0] - bf2f(h[0])), f2bf(v[1] - bf2f(h[1])),
                 f2bf(v[2] - bf2f(h[2])), f2bf(v[3] - bf2f(h[3]))};
      *(u16x4*)&lds[2][row][qd] = l;
    }
    #pragma unroll
    for (int a = 0; a < 2; ++a) {
      int idx = t + 256 * a;
      int row = idx >> 2, c8 = (idx & 3) * 8;
      *(u16x8*)&lds[1][row][c8] = *(const u16x8*)(Bh + (size_t)(n0 + row) * 256 + kb + c8);
      *(u16x8*)&lds[3][row][c8] = *(const u16x8*)(Bl + (size_t)(n0 + row) * 256 + kb + c8);
    }
    __syncthreads();

    bf16x8 ah[4], bh[4], al[4], bl[4];
    #pragma unroll
    for (int i = 0; i < 4; ++i) {
      ah[i] = __builtin_bit_cast(bf16x8, *(const u16x8*)&lds[0][wr * 64 + i * 16 + lr][kq * 8]);
      bh[i] = __builtin_bit_cast(bf16x8, *(const u16x8*)&lds[1][wc * 64 + i * 16 + lr][kq * 8]);
      al[i] = __builtin_bit_cast(bf16x8, *(const u16x8*)&lds[2][wr * 64 + i * 16 + lr][kq * 8]);
      bl[i] = __builtin_bit_cast(bf16x8, *(const u16x8*)&lds[3][wc * 64 + i * 16 + lr][kq * 8]);
    }
    #pragma unroll
    for (int i = 0; i < 4; ++i)
      #pragma unroll
      for (int j = 0; j < 4; ++j) {
        acc[i][j] = __builtin_amdgcn_mfma_f32_16x16x32_bf16(ah[i], bh[j], acc[i][j], 0, 0, 0);
        acc[i][j] = __builtin_amdgcn_mfma_f32_16x16x32_bf16(ah[i], bl[j], acc[i][j], 0, 0, 0);
        acc[i][j] = __builtin_amdgcn_mfma_f32_16x16x32_bf16(al[i], bh[j], acc[i][j], 0, 0, 0);
      }
    __syncthreads();
  }

  #pragma unroll
  for (int i = 0; i < 4; ++i)
    #pragma unroll
    for (int j = 0; j < 4; ++j) {
      float* cp = C + (size_t)(m0 + wr * 64 + i * 16 + kq * 4) * 256 + n0 + wc * 64 + j * 16 + lr;
      #pragma unroll
      for (int qq = 0; qq < 4; ++qq) cp[(size_t)qq * 256] = acc[i][j][qq];
    }
}

// ---------------------------------------------------------------------------
// Mega-prep kernel: one launch covering all independent preprocessing.
//   blocks [0,512):        vproj_hval (np-fp32-exact v hval)
//   blocks [512,640):      8x 256x256 weight transposes
//   blocks [640,12928):    d1 pass (natural + transposed bf16)
//   blocks [12928,19072):  d0 pass (natural + transposed bf16 hi/lo)
// Per-thread arithmetic identical to the R7 standalone kernels.
// ---------------------------------------------------------------------------
struct PrepArgs {
  const float* wsrc[8]; unsigned short* wh[8]; unsigned short* wl[8];
  const float* d1; unsigned short* d1T; unsigned short* d1N;
  const float* d0; unsigned short* d0T_hi; unsigned short* d0T_lo;
  unsigned short* d0N_hi; unsigned short* d0N_lo;
  const float* xv; const float* Wvq; const float* Wvk; float* hvV;
};

__global__ __launch_bounds__(256) void prep_all(PrepArgs A) {
  __shared__ __align__(16) char smem[24576];
  const int t = threadIdx.x;
  const int bid = blockIdx.x;

  if (bid < 512) {
    // ---- vproj (np-fp32 exact, 8 rows/block) ----
    float* sx = (float*)smem;
    float* sq = (float*)(smem + 8192);
    float* sk = (float*)(smem + 16384);
    const int r0 = bid * 8;
    const int j = t;
    #pragma unroll
    for (int r = 0; r < 8; ++r) sx[r * 256 + j] = A.xv[(size_t)(r0 + r) * 256 + j];
    __syncthreads();
    float qa[8] = {}, ka[8] = {};
    for (int i = 0; i < 256; ++i) {
      float wq = A.Wvq[i * 256 + j], wk = A.Wvk[i * 256 + j];
      #pragma unroll
      for (int r = 0; r < 8; ++r) {
        qa[r] = __fmaf_rn(sx[r * 256 + i], wq, qa[r]);
        ka[r] = __fmaf_rn(sx[r * 256 + i], wk, ka[r]);
      }
    }
    #pragma unroll
    for (int r = 0; r < 8; ++r) { sq[r * 256 + j] = qa[r]; sk[r * 256 + j] = ka[r]; }
    __syncthreads();
    if (j < 64) {
      const int r = j >> 3, head = j & 7;
      const float* qq = &sq[r * 256 + head * 32];
      const float* kk = &sk[r * 256 + head * 32];
      float s0 = 0.0f, s1 = 0.0f, s2 = 0.0f, s3 = 0.0f;
      #pragma unroll 1
      for (int d = 0; d < 32; d += 4) {
        s0 = __fadd_rn(s0, __fmul_rn(qq[d + 0], kk[d + 0]));
        s1 = __fadd_rn(s1, __fmul_rn(qq[d + 1], kk[d + 1]));
        s2 = __fadd_rn(s2, __fmul_rn(qq[d + 2], kk[d + 2]));
        s3 = __fadd_rn(s3, __fmul_rn(qq[d + 3], kk[d + 3]));
      }
      float p = __fadd_rn(__fadd_rn(s0, s2), __fadd_rn(s1, s3));
      float hval = __fdiv_rn(p, sqrtf(32.0f));
      float inv = __fdiv_rn(1.0f, __fadd_rn(hval, 1e-6f));
      const int row = r0 + r;
      const int b = row / 2048, pos = row - b * 2048;
      A.hvV[((size_t)b * 8 + head) * 2048 + pos] = inv;
    }
  } else if (bid < 640) {
    // ---- weight transposes: idx -> (w, r0, c0) ----
    const int idx = bid - 512;
    const int w = idx >> 4;
    const int r0 = (idx & 3) * 64, c0 = ((idx >> 2) & 3) * 64;
    const float* src = A.wsrc[w];
    unsigned short* oh = A.wh[w];
    unsigned short* ol = A.wl[w];
    unsigned short (*thi)[72] = (unsigned short (*)[72])smem;
    unsigned short (*tlo)[72] = (unsigned short (*)[72])(smem + 9216);
    #pragma unroll
    for (int a = 0; a < 4; ++a) {
      int idx2 = t + 256 * a;
      int tr = idx2 >> 4, tc = (idx2 & 15) * 4;
      f32x4 v = *(const f32x4*)(src + (size_t)(r0 + tr) * 256 + c0 + tc);
      u16x4 hh = {f2bf(v[0]), f2bf(v[1]), f2bf(v[2]), f2bf(v[3])};
      *(u16x4*)&thi[tr][tc] = hh;
      if (ol) {
        u16x4 ll = {f2bf(v[0] - bf2f(hh[0])), f2bf(v[1] - bf2f(hh[1])),
                    f2bf(v[2] - bf2f(hh[2])), f2bf(v[3] - bf2f(hh[3]))};
        *(u16x4*)&tlo[tr][tc] = ll;
      }
    }
    __syncthreads();
    #pragma unroll
    for (int a = 0; a < 2; ++a) {
      int idx2 = t + 256 * a;
      int orow = idx2 >> 3, oc = (idx2 & 7) * 8;
      u16x8 vh;
      #pragma unroll
      for (int j = 0; j < 8; ++j) vh[j] = thi[oc + j][orow];
      *(u16x8*)(oh + (size_t)(c0 + orow) * 256 + r0 + oc) = vh;
      if (ol) {
        u16x8 vl;
        #pragma unroll
        for (int j = 0; j < 8; ++j) vl[j] = tlo[oc + j][orow];
        *(u16x8*)(ol + (size_t)(c0 + orow) * 256 + r0 + oc) = vl;
      }
    }
  } else if (bid < 12928) {
    // ---- d1: [2][4096][6144] -> d1N (natural bf16) + d1T ([2][6144][4096]) ----
    const int idx = bid - 640;
    const int x = idx & 63;          // 64 face tiles
    const int rem = idx >> 6;
    const int y = rem % 96;          // 96 edge tiles
    const int b = rem / 96;
    const int r0 = x * 64, c0 = y * 64;
    unsigned short (*thi)[72] = (unsigned short (*)[72])smem;
    #pragma unroll
    for (int a = 0; a < 4; ++a) {
      int idx2 = t + 256 * a;
      int tr = idx2 >> 4, tc = (idx2 & 15) * 4;
      size_t off = ((size_t)b * 4096 + r0 + tr) * 6144 + c0 + tc;
      f32x4 v = *(const f32x4*)(A.d1 + off);
      u16x4 hh = {f2bf(v[0]), f2bf(v[1]), f2bf(v[2]), f2bf(v[3])};
      *(u16x4*)&thi[tr][tc] = hh;
      *(u16x4*)(A.d1N + off) = hh;
    }
    __syncthreads();
    #pragma unroll
    for (int a = 0; a < 2; ++a) {
      int idx2 = t + 256 * a;
      int orow = idx2 >> 3, oc = (idx2 & 7) * 8;
      u16x8 vh;
      #pragma unroll
      for (int j = 0; j < 8; ++j) vh[j] = thi[oc + j][orow];
      *(u16x8*)(A.d1T + ((size_t)b * 6144 + c0 + orow) * 4096 + r0 + oc) = vh;
    }
  } else {
    // ---- d0: [2][6144][2048] -> d0N hi/lo + d0T hi/lo ([2][2048][6144]) ----
    const int idx = bid - 12928;
    const int x = idx % 96;          // 96 edge tiles
    const int rem = idx / 96;
    const int y = rem & 31;          // 32 vertex tiles
    const int b = rem >> 5;
    const int r0 = x * 64, c0 = y * 64;
    unsigned short (*thi)[72] = (unsigned short (*)[72])smem;
    unsigned short (*tlo)[72] = (unsigned short (*)[72])(smem + 9216);
    #pragma unroll
    for (int a = 0; a < 4; ++a) {
      int idx2 = t + 256 * a;
      int tr = idx2 >> 4, tc = (idx2 & 15) * 4;
      size_t off = ((size_t)b * 6144 + r0 + tr) * 2048 + c0 + tc;
      f32x4 v = *(const f32x4*)(A.d0 + off);
      u16x4 hh = {f2bf(v[0]), f2bf(v[1]), f2bf(v[2]), f2bf(v[3])};
      u16x4 ll = {f2bf(v[0] - bf2f(hh[0])), f2bf(v[1] - bf2f(hh[1])),
                  f2bf(v[2] - bf2f(hh[2])), f2bf(v[3] - bf2f(hh[3]))};
      *(u16x4*)&thi[tr][tc] = hh;
      *(u16x4*)&tlo[tr][tc] = ll;
      *(u16x4*)(A.d0N_hi + off) = hh;
      *(u16x4*)(A.d0N_lo + off) = ll;
    }
    __syncthreads();
    #pragma unroll
    for (int a = 0; a < 2; ++a) {
      int idx2 = t + 256 * a;
      int orow = idx2 >> 3, oc = (idx2 & 7) * 8;
      u16x8 vh, vl;
      #pragma unroll
      for (int j = 0; j < 8; ++j) { vh[j] = thi[oc + j][orow]; vl[j] = tlo[oc + j][orow]; }
      size_t o = ((size_t)b * 2048 + c0 + orow) * 6144 + r0 + oc;
      *(u16x8*)(A.d0T_hi + o) = vh;
      *(u16x8*)(A.d0T_lo + o) = vl;
    }
  }
}

// ---------------------------------------------------------------------------
// Fused eVT (unscaled bf16) + Y0T (scaled hi/lo) from P1 cols 512..767
// (row stride 1280).
// ---------------------------------------------------------------------------
__global__ __launch_bounds__(256) void xpose_ev(
    const float* __restrict__ P1, unsigned short* __restrict__ eVT,
    unsigned short* __restrict__ yhi, unsigned short* __restrict__ ylo,
    const float* __restrict__ hE) {
  __shared__ unsigned short te[64][72], th[64][72], tl[64][72];
  const int b = blockIdx.z;
  const int r0 = blockIdx.x * 64, c0 = blockIdx.y * 64;
  const int t = threadIdx.x;
  #pragma unroll
  for (int a = 0; a < 4; ++a) {
    int idx = t + 256 * a;
    int tr = idx >> 4, tc = (idx & 15) * 4;
    f32x4 v = *(const f32x4*)(P1 + ((size_t)b * 6144 + r0 + tr) * 1280 + 512 + c0 + tc);
    u16x4 eh = {f2bf(v[0]), f2bf(v[1]), f2bf(v[2]), f2bf(v[3])};
    *(u16x4*)&te[tr][tc] = eh;
    float s = hE[((size_t)b * 8 + ((c0 + tc) >> 5)) * 6144 + r0 + tr];
    f32x4 y = v * s;
    u16x4 hh = {f2bf(y[0]), f2bf(y[1]), f2bf(y[2]), f2bf(y[3])};
    *(u16x4*)&th[tr][tc] = hh;
    u16x4 ll = {f2bf(y[0] - bf2f(hh[0])), f2bf(y[1] - bf2f(hh[1])),
                f2bf(y[2] - bf2f(hh[2])), f2bf(y[3] - bf2f(hh[3]))};
    *(u16x4*)&tl[tr][tc] = ll;
  }
  __syncthreads();
  #pragma unroll
  for (int a = 0; a < 2; ++a) {
    int idx = t + 256 * a;
    int orow = idx >> 3, oc = (idx & 7) * 8;
    u16x8 ve, vh, vl;
    #pragma unroll
    for (int j = 0; j < 8; ++j) {
      ve[j] = te[oc + j][orow];
      vh[j] = th[oc + j][orow];
      vl[j] = tl[oc + j][orow];
    }
    size_t o = ((size_t)b * 256 + c0 + orow) * 6144 + r0 + oc;
    *(u16x8*)(eVT + o) = ve;
    *(u16x8*)(yhi + o) = vh;
    *(u16x8*)(ylo + o) = vl;
  }
}

// ---------------------------------------------------------------------------
// Merged rsc_cvt: blocks [0,2048) do T1 job (S=6, P=4096, hi only);
// blocks [2048,3072) do T3 job (S=12, P=2048, hi+lo). Same per-element math.
// ---------------------------------------------------------------------------
static __device__ __forceinline__ void rsc_body(
    const float* in, unsigned short* out_hi, unsigned short* out_lo,
    const float* h, int S, int R, int P, int bid, int nblk) {
  const long long qP = P >> 2;
  const long long nq = 2LL * R * qP;
  long long i = (long long)bid * 256 + threadIdx.x;
  const long long stride = (long long)nblk * 256;
  for (; i < nq; i += stride) {
    long long b = i / (R * qP);
    long long rem = i - b * (R * qP);
    int row = (int)(rem / qP);
    long long qc = rem - (long long)row * qP;
    const f32x4* base = (const f32x4*)in + ((b * S) * R + row) * qP + qc;
    f32x4 v = base[0];
    for (int s = 1; s < S; ++s) v += base[(long long)s * R * qP];
    v *= *(const f32x4*)(h + ((size_t)b * 8 + (row >> 5)) * P + (qc << 2));
    u16x4 hh = {f2bf(v[0]), f2bf(v[1]), f2bf(v[2]), f2bf(v[3])};
    ((u16x4*)out_hi)[i] = hh;
    if (out_lo) {
      u16x4 ll = {f2bf(v[0] - bf2f(hh[0])), f2bf(v[1] - bf2f(hh[1])),
                  f2bf(v[2] - bf2f(hh[2])), f2bf(v[3] - bf2f(hh[3]))};
      ((u16x4*)out_lo)[i] = ll;
    }
  }
}

__global__ void rsc2(const float* in1, unsigned short* o1h, const float* hF,
                     const float* in3, unsigned short* o3h, unsigned short* o3l,
                     const float* hV) {
  if (blockIdx.x < 2048)
    rsc_body(in1, o1h, nullptr, hF, 6, 256, 4096, blockIdx.x, 2048);
  else
    rsc_body(in3, o3h, o3l, hV, 12, 256, 2048, blockIdx.x - 2048, 1024);
}

// e_hval (cols 0/256) and einv_hval (cols 768/1024) from P1 [12288][1280].
__global__ __launch_bounds__(256) void dot2_hval(
    const float* __restrict__ P1, float* __restrict__ hE,
    float* __restrict__ hEi) {
  const int wv = threadIdx.x >> 6, lane = threadIdx.x & 63;
  const int row = blockIdx.x * 4 + wv;
  const float* base = P1 + (size_t)row * 1280 + lane * 4;
  f32x4 q = *(const f32x4*)(base);
  f32x4 k = *(const f32x4*)(base + 256);
  float p = q[0] * k[0] + q[1] * k[1] + q[2] * k[2] + q[3] * k[3];
  p += __shfl_xor(p, 1); p += __shfl_xor(p, 2); p += __shfl_xor(p, 4);
  f32x4 q2 = *(const f32x4*)(base + 768);
  f32x4 k2 = *(const f32x4*)(base + 1024);
  float p2 = q2[0] * k2[0] + q2[1] * k2[1] + q2[2] * k2[2] + q2[3] * k2[3];
  p2 += __shfl_xor(p2, 1); p2 += __shfl_xor(p2, 2); p2 += __shfl_xor(p2, 4);
  if ((lane & 7) == 0) {
    const int head = lane >> 3;
    const int b = row / 6144, pos = row % 6144;
    hE[((size_t)b * 8 + head) * 6144 + pos] = p * 0.17677669529663687f;
    hEi[((size_t)b * 8 + head) * 6144 + pos] = p2 * 0.17677669529663687f;
  }
}

// hval = rowwise per-head dot of fp32 Q,K (ld = row stride). One wave/row.
__global__ __launch_bounds__(256) void dot_hval(
    const float* __restrict__ Q, const float* __restrict__ K,
    float* __restrict__ hout, int P, int ld) {
  const int wv = threadIdx.x >> 6, lane = threadIdx.x & 63;
  const int row = blockIdx.x * 4 + wv;
  f32x4 q = *(const f32x4*)(Q + (size_t)row * ld + lane * 4);
  f32x4 k = *(const f32x4*)(K + (size_t)row * ld + lane * 4);
  float p = q[0] * k[0] + q[1] * k[1] + q[2] * k[2] + q[3] * k[3];
  p += __shfl_xor(p, 1); p += __shfl_xor(p, 2); p += __shfl_xor(p, 4);
  if ((lane & 7) == 0) {
    const int head = lane >> 3;
    const int b = row / P, pos = row % P;
    hout[((size_t)b * 8 + head) * P + pos] = p * 0.17677669529663687f;
  }
}

// ---------------------------------------------------------------------------
extern "C" void kernel_launch(void* const* d_in, const int* in_sizes, int n_in,
                              void* d_out, int out_size, void* d_ws, size_t ws_size,
                              hipStream_t stream) {
  const float* x_v = (const float*)d_in[0];
  const float* x_e = (const float*)d_in[1];
  const float* x_f = (const float*)d_in[2];
  const float* d0  = (const float*)d_in[3];   // (2, 6144, 2048)
  const float* d1  = (const float*)d_in[4];   // (2, 4096, 6144)
  float* out = (float*)d_out;

  const int NV = 2048, ME = 6144, KF = 4096;
  const float* NF = nullptr;
  const unsigned short* NUS = nullptr;

  char* ws = (char*)d_ws;
  size_t o = 0;
  auto alloc = [&](size_t bytes) { size_t r = o; o = (o + bytes + 255) & ~255ULL; return r; };

  unsigned short* Wcat5_hi = (unsigned short*)(ws + alloc(1280 * 256 * 2));
  unsigned short* Wcat5_lo = (unsigned short*)(ws + alloc(1280 * 256 * 2));
  unsigned short* W3_hi = (unsigned short*)(ws + alloc(512 * 256 * 2));
  unsigned short* Wo_hi = (unsigned short*)(ws + alloc(256 * 256 * 2));
  unsigned short* Wo_lo = (unsigned short*)(ws + alloc(256 * 256 * 2));
  float* pHvE  = (float*)(ws + alloc(2 * 8 * ME * 4));
  float* pHvEi = (float*)(ws + alloc(2 * 8 * ME * 4));
  float* pHvF  = (float*)(ws + alloc(2 * 8 * KF * 4));
  float* pHvV  = (float*)(ws + alloc(2 * 8 * NV * 4));
  unsigned short* d1T_hi = (unsigned short*)(ws + alloc((size_t)2 * ME * KF * 2));   // [2][6144][4096]
  unsigned short* d1N_hi = (unsigned short*)(ws + alloc((size_t)2 * KF * ME * 2));   // [2][4096][6144]
  unsigned short* d0T_hi = (unsigned short*)(ws + alloc((size_t)2 * NV * ME * 2));   // [2][2048][6144]
  unsigned short* d0T_lo = (unsigned short*)(ws + alloc((size_t)2 * NV * ME * 2));
  unsigned short* d0N_hi = (unsigned short*)(ws + alloc((size_t)2 * ME * NV * 2));   // [2][6144][2048]
  unsigned short* d0N_lo = (unsigned short*)(ws + alloc((size_t)2 * ME * NV * 2));
  unsigned short* eVT_hi = (unsigned short*)(ws + alloc((size_t)2 * 256 * ME * 2));  // [2][256][6144]
  unsigned short* Y0T_hi = (unsigned short*)(ws + alloc((size_t)2 * 256 * ME * 2));
  unsigned short* Y0T_lo = (unsigned short*)(ws + alloc((size_t)2 * 256 * ME * 2));
  unsigned short* T1sT_hi = (unsigned short*)(ws + alloc((size_t)2 * 256 * KF * 2)); // [2][256][4096]
  unsigned short* T3sT_hi = (unsigned short*)(ws + alloc((size_t)2 * 256 * NV * 2)); // [2][256][2048]
  unsigned short* T3sT_lo = (unsigned short*)(ws + alloc((size_t)2 * 256 * NV * 2));
  float* pP1 = (float*)(ws + alloc((size_t)12288 * 1280 * 4));   // e projections (N=1280)
  float* pP3 = (float*)(ws + alloc((size_t)8192 * 512 * 4));     // f projections
  float* pTp1 = (float*)(ws + alloc((size_t)2 * 6 * 256 * KF * 4));   // T1^T slabs
  float* pTp3 = (float*)(ws + alloc((size_t)2 * 12 * 256 * NV * 4));  // T3^T slabs
  float* pT2p = (float*)(ws + alloc((size_t)2 * 4 * ME * 256 * 4));
  float* pT4p = (float*)(ws + alloc((size_t)2 * 4 * ME * 256 * 4));

  dim3 blk(256);

  // --- mega-prep: vproj + weight transposes + d1/d0 conversions ---
  PrepArgs pa;
  pa.wsrc[0] = (const float*)d_in[7];  pa.wh[0] = Wcat5_hi;          pa.wl[0] = Wcat5_lo;          // eq
  pa.wsrc[1] = (const float*)d_in[8];  pa.wh[1] = Wcat5_hi + 65536;  pa.wl[1] = Wcat5_lo + 65536;  // ek
  pa.wsrc[2] = (const float*)d_in[11]; pa.wh[2] = Wcat5_hi + 131072; pa.wl[2] = Wcat5_lo + 131072; // ev
  pa.wsrc[3] = (const float*)d_in[9];  pa.wh[3] = Wcat5_hi + 196608; pa.wl[3] = Wcat5_lo + 196608; // einvq
  pa.wsrc[4] = (const float*)d_in[10]; pa.wh[4] = Wcat5_hi + 262144; pa.wl[4] = Wcat5_lo + 262144; // einvk
  pa.wsrc[5] = (const float*)d_in[12]; pa.wh[5] = W3_hi;             pa.wl[5] = nullptr;           // fq
  pa.wsrc[6] = (const float*)d_in[13]; pa.wh[6] = W3_hi + 65536;     pa.wl[6] = nullptr;           // fk
  pa.wsrc[7] = (const float*)d_in[14]; pa.wh[7] = Wo_hi;             pa.wl[7] = Wo_lo;             // o
  pa.d1 = d1; pa.d1T = d1T_hi; pa.d1N = d1N_hi;
  pa.d0 = d0; pa.d0T_hi = d0T_hi; pa.d0T_lo = d0T_lo;
  pa.d0N_hi = d0N_hi; pa.d0N_lo = d0N_lo;
  pa.xv = x_v; pa.Wvq = (const float*)d_in[5]; pa.Wvk = (const float*)d_in[6];
  pa.hvV = pHvV;
  prep_all<<<19072, blk, 0, stream>>>(pa);

  // --- projections: P1 = x_e @ [eq|ek|ev|einvq|einvk] (split), P3 = x_f @ [fq|fk] ---
  gemm_ws<false, true, false><<<dim3(96, 10, 1), blk, 0, stream>>>(
      x_e, NUS, NUS, Wcat5_hi, Wcat5_lo, pP1, 256, 256, 256, 1, 0, 0, 0);
  gemm_ws<false, false, false><<<dim3(64, 4, 1), blk, 0, stream>>>(
      x_f, NUS, NUS, W3_hi, NUS, pP3, 256, 256, 256, 1, 0, 0, 0);
  dot2_hval<<<3072, blk, 0, stream>>>(pP1, pHvE, pHvEi);
  dot_hval<<<2048, blk, 0, stream>>>(pP3, pP3 + 256, pHvF, KF, 512);
  xpose_ev<<<dim3(96, 4, 2), blk, 0, stream>>>(pP1, eVT_hi, Y0T_hi, Y0T_lo, pHvE);

  // --- T1 || T3 (independent big GEMMs, tail overlap) ---
  // T1^T = eVT @ d1N (plain), S=6 -> [2][6][256][4096]
  gemm_ws<true, false, true><<<dim3(2, 32, 12), blk, 0, stream>>>(
      NF, eVT_hi, NUS, d1N_hi, NUS, pTp1, ME, ME, ME, 6,
      256LL * ME, (long long)KF * ME, 256LL * KF);
  // T3^T = Y0T @ d0T (split), S=12 -> [2][12][256][2048]
  gemm_ws<true, true, true><<<dim3(2, 16, 24), blk, 0, stream>>>(
      NF, Y0T_hi, Y0T_lo, d0T_hi, d0T_lo, pTp3, ME, ME, ME, 12,
      256LL * ME, (long long)NV * ME, 256LL * NV);

  // --- merged reductions + scale + cvt ---
  rsc2<<<3072, blk, 0, stream>>>(pTp1, T1sT_hi, pHvF, pTp3, T3sT_hi, T3sT_lo, pHvV);

  // --- T2 || T4 ---
  // T2 = d1T @ T1s (plain), S=4 -> [2][4][6144][256]
  gemm_ws<true, false, false><<<dim3(48, 2, 8), blk, 0, stream>>>(
      NF, d1T_hi, NUS, T1sT_hi, NUS, pT2p, KF, KF, KF, 4,
      (long long)ME * KF, 256LL * KF, (long long)ME * 256);
  // T4 = d0N @ T3s (split), S=4 -> [2][4][6144][256]
  gemm_ws<true, true, false><<<dim3(48, 2, 8), blk, 0, stream>>>(
      NF, d0N_hi, d0N_lo, T3sT_hi, T3sT_lo, pT4p, NV, NV, NV, 4,
      (long long)ME * NV, 256LL * NV, (long long)ME * 256);

  // --- fused combine + output projection ---
  gemm_out<<<dim3(96, 2, 1), blk, 0, stream>>>(pT2p, pT4p, pHvEi, Wo_hi, Wo_lo, out);
}

// Round 10
// 431.134 us; speedup vs baseline: 1.3235x; 1.1630x over previous
//
#include <hip/hip_runtime.h>
#include <hip/hip_bf16.h>
#include <cstdint>
#include <cstddef>

// ---------------------------------------------------------------------------
// MeshMultiHeadHodgeLaplaceAttention  (b=2, n=2048, m=6144, k=4096, D=256, H=8)
//
//   up:   T1 = d_1 @ eV ; *f_hval ; T2 = d_1^T @ T1s ; (*einv_hval in combine)
//   down: Y0 = eV*e_hval ; T3 = d_0^T @ Y0 ; *1/(v_hval+eps) ; T4 = d_0 @ T3s
//   out = (T2*einv_hval + T4) @ W_o
//
// Precision: v_hval replicates numpy fp32 bit-exactly (R3); projections P1 and
// the output GEMM keep split-bf16; T1..T4 plain bf16 (R1->R2 showed the whole
// chain's split-vs-plain delta is ~130 absolute vs threshold 793.6).
//
// R10: plain-precision T3/T4 (-52 GFLOP, half the LDS); dual-job GEMM
// launches (T1+T3, T2+T4) for real overlap (same-stream kernels serialize);
// prep drops all lo-buffer writes (-150 MB).
// ---------------------------------------------------------------------------

typedef __attribute__((ext_vector_type(4))) float f32x4;
typedef __attribute__((ext_vector_type(4))) unsigned short u16x4;
typedef __attribute__((ext_vector_type(8))) unsigned short u16x8;
typedef __attribute__((ext_vector_type(8))) __bf16 bf16x8;

static __device__ __forceinline__ unsigned short f2bf(float f) {
  uint32_t u = __builtin_bit_cast(uint32_t, f);
  uint32_t r = (u + 0x7FFFu + ((u >> 16) & 1u)) >> 16;  // RNE
  return (unsigned short)r;
}
static __device__ __forceinline__ float bf2f(unsigned short h) {
  return __builtin_bit_cast(float, (uint32_t)h << 16);
}

// ---------------------------------------------------------------------------
// Dual-job plain-bf16 GEMM. Two independent jobs packed into one launch
// (same-stream kernels serialize; this is the only way to overlap them).
// Per job: C[M x gy*128] = A[M x K] (bf16 [M][K]) * B (bf16 [N][K]).
// Split-K: z = batch*S + split, slab per z. 128x128 tile, reg-prefetch.
// ---------------------------------------------------------------------------
struct GJob {
  const unsigned short* Ah; const unsigned short* Bh; float* C;
  int K, ldA, ldB, S, gx, gy;
  long long sA, sB, sC;
};

template <bool XFAST>
__global__ __launch_bounds__(256) void gemm_dual(GJob j0, GJob j1, int nb0) {
  const bool first = (int)blockIdx.x < nb0;
  GJob J = first ? j0 : j1;
  const int b = first ? blockIdx.x : blockIdx.x - nb0;
  const int per = J.gx * J.gy;
  const int z = b / per;
  const int wid = b - z * per;
  const int batch = z / J.S, split = z - batch * J.S;
  const unsigned short* Ah = J.Ah + (long long)batch * J.sA;
  const unsigned short* Bh = J.Bh + (long long)batch * J.sB;
  float* C = J.C + (long long)z * J.sC;

  // XCD-bijective swizzle within this job's z-slice
  const int nwg = per;
  const int q = nwg >> 3, r = nwg & 7;
  const int xcd = wid & 7, posn = wid >> 3;
  const int swz = (xcd < r ? xcd * (q + 1) : r * (q + 1) + (xcd - r) * q) + posn;
  int mt, nt;
  if constexpr (XFAST) { mt = swz % J.gx; nt = swz / J.gx; }
  else                 { mt = swz / J.gy; nt = swz - mt * J.gy; }
  const int m0 = mt * 128, n0 = nt * 128;
  const int NC = J.gy << 7;
  const int kLen = J.K / J.S, k0base = split * kLen;

  __shared__ unsigned short lds[2][128][40];

  const int t = threadIdx.x;
  const int w4 = t >> 6, lane = t & 63;
  const int wr = w4 >> 1, wc = w4 & 1;
  const int lr = lane & 15, kq = lane >> 4;
  const int rowV = t >> 2, c8V = (t & 3) * 8;

  u16x8 rA[2], rB[2];
  auto LOAD = [&](int kb) {
    #pragma unroll
    for (int a = 0; a < 2; ++a) {
      rA[a] = *(const u16x8*)(Ah + (size_t)(m0 + rowV + 64 * a) * J.ldA + kb + c8V);
      rB[a] = *(const u16x8*)(Bh + (size_t)(n0 + rowV + 64 * a) * J.ldB + kb + c8V);
    }
  };
  auto STORE = [&]() {
    #pragma unroll
    for (int a = 0; a < 2; ++a) {
      *(u16x8*)&lds[0][rowV + 64 * a][c8V] = rA[a];
      *(u16x8*)&lds[1][rowV + 64 * a][c8V] = rB[a];
    }
  };

  f32x4 acc[4][4] = {};
  LOAD(k0base);
  for (int kk = 0; kk < kLen; kk += 32) {
    STORE();
    __syncthreads();
    if (kk + 32 < kLen) LOAD(k0base + kk + 32);  // prefetch under MFMA

    bf16x8 ah[4], bh[4];
    #pragma unroll
    for (int i = 0; i < 4; ++i) {
      ah[i] = __builtin_bit_cast(bf16x8, *(const u16x8*)&lds[0][wr * 64 + i * 16 + lr][kq * 8]);
      bh[i] = __builtin_bit_cast(bf16x8, *(const u16x8*)&lds[1][wc * 64 + i * 16 + lr][kq * 8]);
    }
    #pragma unroll
    for (int i = 0; i < 4; ++i)
      #pragma unroll
      for (int j = 0; j < 4; ++j)
        acc[i][j] = __builtin_amdgcn_mfma_f32_16x16x32_bf16(ah[i], bh[j], acc[i][j], 0, 0, 0);
    __syncthreads();
  }

  // epilogue: D mapping col = lane&15, row = (lane>>4)*4 + q
  #pragma unroll
  for (int i = 0; i < 4; ++i)
    #pragma unroll
    for (int j = 0; j < 4; ++j) {
      float* cp = C + (size_t)(m0 + wr * 64 + i * 16 + kq * 4) * NC + n0 + wc * 64 + j * 16 + lr;
      #pragma unroll
      for (int qq = 0; qq < 4; ++qq) cp[(size_t)qq * NC] = acc[i][j][qq];
    }
}

// ---------------------------------------------------------------------------
// gemm_ws: projection GEMMs. A fp32 [M][K] cvt-in-staging; B bf16 hi(/lo).
// ---------------------------------------------------------------------------
template <bool SPLIT>
__global__ __launch_bounds__(256) void gemm_ws(
    const float* __restrict__ Af,
    const unsigned short* __restrict__ Bh, const unsigned short* __restrict__ Bl,
    float* __restrict__ C, int K, int ldA, int ldB,
    long long sA, long long sB, long long sC) {
  const int gx = gridDim.x, gy = gridDim.y;
  const int nwg = gx * gy;
  const int wid = blockIdx.x + gx * blockIdx.y;
  const int q = nwg >> 3, r = nwg & 7;
  const int xcd = wid & 7, posn = wid >> 3;
  const int swz = (xcd < r ? xcd * (q + 1) : r * (q + 1) + (xcd - r) * q) + posn;
  const int mt = swz / gy;
  const int m0 = mt * 128, n0 = (swz - mt * gy) * 128;
  const int NC = gy << 7;

  constexpr int NBUF = SPLIT ? 4 : 2;
  __shared__ unsigned short lds[NBUF][128][40];

  const int t = threadIdx.x;
  const int w4 = t >> 6, lane = t & 63;
  const int wr = w4 >> 1, wc = w4 & 1;
  const int lr = lane & 15, kq = lane >> 4;
  const int rowA8 = t >> 3, qdA = (t & 7) * 4;
  const int rowV = t >> 2, c8V = (t & 3) * 8;

  f32x4 rAf[4];
  u16x8 rBh[2], rBl[2];

  auto LOAD = [&](int kb) {
    #pragma unroll
    for (int a = 0; a < 4; ++a)
      rAf[a] = *(const f32x4*)(Af + (size_t)(m0 + rowA8 + 32 * a) * ldA + kb + qdA);
    #pragma unroll
    for (int a = 0; a < 2; ++a) {
      rBh[a] = *(const u16x8*)(Bh + (size_t)(n0 + rowV + 64 * a) * ldB + kb + c8V);
      if constexpr (SPLIT)
        rBl[a] = *(const u16x8*)(Bl + (size_t)(n0 + rowV + 64 * a) * ldB + kb + c8V);
    }
  };
  auto STORE = [&]() {
    #pragma unroll
    for (int a = 0; a < 4; ++a) {
      f32x4 v = rAf[a];
      u16x4 h = {f2bf(v[0]), f2bf(v[1]), f2bf(v[2]), f2bf(v[3])};
      *(u16x4*)&lds[0][rowA8 + 32 * a][qdA] = h;
      if constexpr (SPLIT) {
        u16x4 l = {f2bf(v[0] - bf2f(h[0])), f2bf(v[1] - bf2f(h[1])),
                   f2bf(v[2] - bf2f(h[2])), f2bf(v[3] - bf2f(h[3]))};
        *(u16x4*)&lds[2][rowA8 + 32 * a][qdA] = l;
      }
    }
    #pragma unroll
    for (int a = 0; a < 2; ++a) {
      *(u16x8*)&lds[1][rowV + 64 * a][c8V] = rBh[a];
      if constexpr (SPLIT) *(u16x8*)&lds[3][rowV + 64 * a][c8V] = rBl[a];
    }
  };

  f32x4 acc[4][4] = {};
  LOAD(0);
  for (int kk = 0; kk < K; kk += 32) {
    STORE();
    __syncthreads();
    if (kk + 32 < K) LOAD(kk + 32);

    bf16x8 ah[4], bh[4], al[4], bl[4];
    #pragma unroll
    for (int i = 0; i < 4; ++i) {
      ah[i] = __builtin_bit_cast(bf16x8, *(const u16x8*)&lds[0][wr * 64 + i * 16 + lr][kq * 8]);
      bh[i] = __builtin_bit_cast(bf16x8, *(const u16x8*)&lds[1][wc * 64 + i * 16 + lr][kq * 8]);
      if constexpr (SPLIT) {
        al[i] = __builtin_bit_cast(bf16x8, *(const u16x8*)&lds[2][wr * 64 + i * 16 + lr][kq * 8]);
        bl[i] = __builtin_bit_cast(bf16x8, *(const u16x8*)&lds[3][wc * 64 + i * 16 + lr][kq * 8]);
      }
    }
    #pragma unroll
    for (int i = 0; i < 4; ++i)
      #pragma unroll
      for (int j = 0; j < 4; ++j) {
        acc[i][j] = __builtin_amdgcn_mfma_f32_16x16x32_bf16(ah[i], bh[j], acc[i][j], 0, 0, 0);
        if constexpr (SPLIT) {
          acc[i][j] = __builtin_amdgcn_mfma_f32_16x16x32_bf16(ah[i], bl[j], acc[i][j], 0, 0, 0);
          acc[i][j] = __builtin_amdgcn_mfma_f32_16x16x32_bf16(al[i], bh[j], acc[i][j], 0, 0, 0);
        }
      }
    __syncthreads();
  }

  #pragma unroll
  for (int i = 0; i < 4; ++i)
    #pragma unroll
    for (int j = 0; j < 4; ++j) {
      float* cp = C + (size_t)(m0 + wr * 64 + i * 16 + kq * 4) * NC + n0 + wc * 64 + j * 16 + lr;
      #pragma unroll
      for (int qq = 0; qq < 4; ++qq) cp[(size_t)qq * NC] = acc[i][j][qq];
    }
}

// ---------------------------------------------------------------------------
// Output GEMM with fused combine: A[r][c] = (T4p 4-slab sum) +
// (T2p 4-slab sum)*einv_hval;  C = A @ W_o (split hi/lo). M=12288,N=256,K=256.
// ---------------------------------------------------------------------------
__global__ __launch_bounds__(256) void gemm_out(
    const float* __restrict__ T2p, const float* __restrict__ T4p,
    const float* __restrict__ hEi, const unsigned short* __restrict__ Bh,
    const unsigned short* __restrict__ Bl, float* __restrict__ C) {
  const int gx = gridDim.x, gy = gridDim.y;
  const int nwg = gx * gy;
  const int wid = blockIdx.x + gx * blockIdx.y;
  const int q = nwg >> 3, r = nwg & 7;
  const int xcd = wid & 7, posn = wid >> 3;
  const int swz = (xcd < r ? xcd * (q + 1) : r * (q + 1) + (xcd - r) * q) + posn;
  const int mt = swz / gy;
  const int m0 = mt * 128, n0 = (swz - mt * gy) * 128;

  __shared__ unsigned short lds[4][128][40];
  const int t = threadIdx.x;
  const int w4 = t >> 6, lane = t & 63;
  const int wr = w4 >> 1, wc = w4 & 1;
  const int lr = lane & 15, kq = lane >> 4;
  const long long slab = 6144LL * 256;

  f32x4 acc[4][4] = {};

  for (int kb = 0; kb < 256; kb += 32) {
    #pragma unroll
    for (int a = 0; a < 4; ++a) {
      int idx = t + 256 * a;
      int row = idx >> 3, qd = (idx & 7) * 4;
      int rg = m0 + row;
      int b = rg >= 6144;
      int pos = rg - b * 6144;
      int ck = kb + qd;
      float s = hEi[((size_t)b * 8 + (ck >> 5)) * 6144 + pos];
      const float* b2 = T2p + ((long long)(b * 4) * 6144 + pos) * 256 + ck;
      const float* b4 = T4p + ((long long)(b * 4) * 6144 + pos) * 256 + ck;
      f32x4 t2 = (*(const f32x4*)b2 + *(const f32x4*)(b2 + slab)) +
                 (*(const f32x4*)(b2 + 2 * slab) + *(const f32x4*)(b2 + 3 * slab));
      f32x4 t4 = (*(const f32x4*)b4 + *(const f32x4*)(b4 + slab)) +
                 (*(const f32x4*)(b4 + 2 * slab) + *(const f32x4*)(b4 + 3 * slab));
      f32x4 v = t4 + t2 * s;
      u16x4 h = {f2bf(v[0]), f2bf(v[1]), f2bf(v[2]), f2bf(v[3])};
      *(u16x4*)&lds[0][row][qd] = h;
      u16x4 l = {f2bf(v[0] - bf2f(h[0])), f2bf(v[1] - bf2f(h[1])),
                 f2bf(v[2] - bf2f(h[2])), f2bf(v[3] - bf2f(h[3]))};
      *(u16x4*)&lds[2][row][qd] = l;
    }
    #pragma unroll
    for (int a = 0; a < 2; ++a) {
      int idx = t + 256 * a;
      int row = idx >> 2, c8 = (idx & 3) * 8;
      *(u16x8*)&lds[1][row][c8] = *(const u16x8*)(Bh + (size_t)(n0 + row) * 256 + kb + c8);
      *(u16x8*)&lds[3][row][c8] = *(const u16x8*)(Bl + (size_t)(n0 + row) * 256 + kb + c8);
    }
    __syncthreads();

    bf16x8 ah[4], bh[4], al[4], bl[4];
    #pragma unroll
    for (int i = 0; i < 4; ++i) {
      ah[i] = __builtin_bit_cast(bf16x8, *(const u16x8*)&lds[0][wr * 64 + i * 16 + lr][kq * 8]);
      bh[i] = __builtin_bit_cast(bf16x8, *(const u16x8*)&lds[1][wc * 64 + i * 16 + lr][kq * 8]);
      al[i] = __builtin_bit_cast(bf16x8, *(const u16x8*)&lds[2][wr * 64 + i * 16 + lr][kq * 8]);
      bl[i] = __builtin_bit_cast(bf16x8, *(const u16x8*)&lds[3][wc * 64 + i * 16 + lr][kq * 8]);
    }
    #pragma unroll
    for (int i = 0; i < 4; ++i)
      #pragma unroll
      for (int j = 0; j < 4; ++j) {
        acc[i][j] = __builtin_amdgcn_mfma_f32_16x16x32_bf16(ah[i], bh[j], acc[i][j], 0, 0, 0);
        acc[i][j] = __builtin_amdgcn_mfma_f32_16x16x32_bf16(ah[i], bl[j], acc[i][j], 0, 0, 0);
        acc[i][j] = __builtin_amdgcn_mfma_f32_16x16x32_bf16(al[i], bh[j], acc[i][j], 0, 0, 0);
      }
    __syncthreads();
  }

  #pragma unroll
  for (int i = 0; i < 4; ++i)
    #pragma unroll
    for (int j = 0; j < 4; ++j) {
      float* cp = C + (size_t)(m0 + wr * 64 + i * 16 + kq * 4) * 256 + n0 + wc * 64 + j * 16 + lr;
      #pragma unroll
      for (int qq = 0; qq < 4; ++qq) cp[(size_t)qq * 256] = acc[i][j][qq];
    }
}

// ---------------------------------------------------------------------------
// Mega-prep kernel (R9), lo-writes removed:
//   [0,512): vproj_hval ; [512,640): weight transposes ;
//   [640,12928): d1 -> d1N + d1T ; [12928,19072): d0 -> d0N_hi + d0T_hi.
// ---------------------------------------------------------------------------
struct PrepArgs {
  const float* wsrc[8]; unsigned short* wh[8]; unsigned short* wl[8];
  const float* d1; unsigned short* d1T; unsigned short* d1N;
  const float* d0; unsigned short* d0T_hi; unsigned short* d0N_hi;
  const float* xv; const float* Wvq; const float* Wvk; float* hvV;
};

__global__ __launch_bounds__(256) void prep_all(PrepArgs A) {
  __shared__ __align__(16) char smem[24576];
  const int t = threadIdx.x;
  const int bid = blockIdx.x;

  if (bid < 512) {
    float* sx = (float*)smem;
    float* sq = (float*)(smem + 8192);
    float* sk = (float*)(smem + 16384);
    const int r0 = bid * 8;
    const int j = t;
    #pragma unroll
    for (int r = 0; r < 8; ++r) sx[r * 256 + j] = A.xv[(size_t)(r0 + r) * 256 + j];
    __syncthreads();
    float qa[8] = {}, ka[8] = {};
    for (int i = 0; i < 256; ++i) {
      float wq = A.Wvq[i * 256 + j], wk = A.Wvk[i * 256 + j];
      #pragma unroll
      for (int r = 0; r < 8; ++r) {
        qa[r] = __fmaf_rn(sx[r * 256 + i], wq, qa[r]);
        ka[r] = __fmaf_rn(sx[r * 256 + i], wk, ka[r]);
      }
    }
    #pragma unroll
    for (int r = 0; r < 8; ++r) { sq[r * 256 + j] = qa[r]; sk[r * 256 + j] = ka[r]; }
    __syncthreads();
    if (j < 64) {
      const int r = j >> 3, head = j & 7;
      const float* qq = &sq[r * 256 + head * 32];
      const float* kk = &sk[r * 256 + head * 32];
      float s0 = 0.0f, s1 = 0.0f, s2 = 0.0f, s3 = 0.0f;
      #pragma unroll 1
      for (int d = 0; d < 32; d += 4) {
        s0 = __fadd_rn(s0, __fmul_rn(qq[d + 0], kk[d + 0]));
        s1 = __fadd_rn(s1, __fmul_rn(qq[d + 1], kk[d + 1]));
        s2 = __fadd_rn(s2, __fmul_rn(qq[d + 2], kk[d + 2]));
        s3 = __fadd_rn(s3, __fmul_rn(qq[d + 3], kk[d + 3]));
      }
      float p = __fadd_rn(__fadd_rn(s0, s2), __fadd_rn(s1, s3));
      float hval = __fdiv_rn(p, sqrtf(32.0f));
      float inv = __fdiv_rn(1.0f, __fadd_rn(hval, 1e-6f));
      const int row = r0 + r;
      const int b = row / 2048, pos = row - b * 2048;
      A.hvV[((size_t)b * 8 + head) * 2048 + pos] = inv;
    }
  } else if (bid < 640) {
    const int idx = bid - 512;
    const int w = idx >> 4;
    const int r0 = (idx & 3) * 64, c0 = ((idx >> 2) & 3) * 64;
    const float* src = A.wsrc[w];
    unsigned short* oh = A.wh[w];
    unsigned short* ol = A.wl[w];
    unsigned short (*thi)[72] = (unsigned short (*)[72])smem;
    unsigned short (*tlo)[72] = (unsigned short (*)[72])(smem + 9216);
    #pragma unroll
    for (int a = 0; a < 4; ++a) {
      int idx2 = t + 256 * a;
      int tr = idx2 >> 4, tc = (idx2 & 15) * 4;
      f32x4 v = *(const f32x4*)(src + (size_t)(r0 + tr) * 256 + c0 + tc);
      u16x4 hh = {f2bf(v[0]), f2bf(v[1]), f2bf(v[2]), f2bf(v[3])};
      *(u16x4*)&thi[tr][tc] = hh;
      if (ol) {
        u16x4 ll = {f2bf(v[0] - bf2f(hh[0])), f2bf(v[1] - bf2f(hh[1])),
                    f2bf(v[2] - bf2f(hh[2])), f2bf(v[3] - bf2f(hh[3]))};
        *(u16x4*)&tlo[tr][tc] = ll;
      }
    }
    __syncthreads();
    #pragma unroll
    for (int a = 0; a < 2; ++a) {
      int idx2 = t + 256 * a;
      int orow = idx2 >> 3, oc = (idx2 & 7) * 8;
      u16x8 vh;
      #pragma unroll
      for (int j = 0; j < 8; ++j) vh[j] = thi[oc + j][orow];
      *(u16x8*)(oh + (size_t)(c0 + orow) * 256 + r0 + oc) = vh;
      if (ol) {
        u16x8 vl;
        #pragma unroll
        for (int j = 0; j < 8; ++j) vl[j] = tlo[oc + j][orow];
        *(u16x8*)(ol + (size_t)(c0 + orow) * 256 + r0 + oc) = vl;
      }
    }
  } else if (bid < 12928) {
    const int idx = bid - 640;
    const int x = idx & 63;
    const int rem = idx >> 6;
    const int y = rem % 96;
    const int b = rem / 96;
    const int r0 = x * 64, c0 = y * 64;
    unsigned short (*thi)[72] = (unsigned short (*)[72])smem;
    #pragma unroll
    for (int a = 0; a < 4; ++a) {
      int idx2 = t + 256 * a;
      int tr = idx2 >> 4, tc = (idx2 & 15) * 4;
      size_t off = ((size_t)b * 4096 + r0 + tr) * 6144 + c0 + tc;
      f32x4 v = *(const f32x4*)(A.d1 + off);
      u16x4 hh = {f2bf(v[0]), f2bf(v[1]), f2bf(v[2]), f2bf(v[3])};
      *(u16x4*)&thi[tr][tc] = hh;
      *(u16x4*)(A.d1N + off) = hh;
    }
    __syncthreads();
    #pragma unroll
    for (int a = 0; a < 2; ++a) {
      int idx2 = t + 256 * a;
      int orow = idx2 >> 3, oc = (idx2 & 7) * 8;
      u16x8 vh;
      #pragma unroll
      for (int j = 0; j < 8; ++j) vh[j] = thi[oc + j][orow];
      *(u16x8*)(A.d1T + ((size_t)b * 6144 + c0 + orow) * 4096 + r0 + oc) = vh;
    }
  } else {
    const int idx = bid - 12928;
    const int x = idx % 96;
    const int rem = idx / 96;
    const int y = rem & 31;
    const int b = rem >> 5;
    const int r0 = x * 64, c0 = y * 64;
    unsigned short (*thi)[72] = (unsigned short (*)[72])smem;
    #pragma unroll
    for (int a = 0; a < 4; ++a) {
      int idx2 = t + 256 * a;
      int tr = idx2 >> 4, tc = (idx2 & 15) * 4;
      size_t off = ((size_t)b * 6144 + r0 + tr) * 2048 + c0 + tc;
      f32x4 v = *(const f32x4*)(A.d0 + off);
      u16x4 hh = {f2bf(v[0]), f2bf(v[1]), f2bf(v[2]), f2bf(v[3])};
      *(u16x4*)&thi[tr][tc] = hh;
      *(u16x4*)(A.d0N_hi + off) = hh;
    }
    __syncthreads();
    #pragma unroll
    for (int a = 0; a < 2; ++a) {
      int idx2 = t + 256 * a;
      int orow = idx2 >> 3, oc = (idx2 & 7) * 8;
      u16x8 vh;
      #pragma unroll
      for (int j = 0; j < 8; ++j) vh[j] = thi[oc + j][orow];
      *(u16x8*)(A.d0T_hi + ((size_t)b * 2048 + c0 + orow) * 6144 + r0 + oc) = vh;
    }
  }
}

// ---------------------------------------------------------------------------
// Fused eVT (unscaled bf16) + Y0T (scaled bf16) from P1 cols 512..767.
// ---------------------------------------------------------------------------
__global__ __launch_bounds__(256) void xpose_ev(
    const float* __restrict__ P1, unsigned short* __restrict__ eVT,
    unsigned short* __restrict__ yhi, const float* __restrict__ hE) {
  __shared__ unsigned short te[64][72], th[64][72];
  const int b = blockIdx.z;
  const int r0 = blockIdx.x * 64, c0 = blockIdx.y * 64;
  const int t = threadIdx.x;
  #pragma unroll
  for (int a = 0; a < 4; ++a) {
    int idx = t + 256 * a;
    int tr = idx >> 4, tc = (idx & 15) * 4;
    f32x4 v = *(const f32x4*)(P1 + ((size_t)b * 6144 + r0 + tr) * 1280 + 512 + c0 + tc);
    u16x4 eh = {f2bf(v[0]), f2bf(v[1]), f2bf(v[2]), f2bf(v[3])};
    *(u16x4*)&te[tr][tc] = eh;
    float s = hE[((size_t)b * 8 + ((c0 + tc) >> 5)) * 6144 + r0 + tr];
    f32x4 y = v * s;
    u16x4 hh = {f2bf(y[0]), f2bf(y[1]), f2bf(y[2]), f2bf(y[3])};
    *(u16x4*)&th[tr][tc] = hh;
  }
  __syncthreads();
  #pragma unroll
  for (int a = 0; a < 2; ++a) {
    int idx = t + 256 * a;
    int orow = idx >> 3, oc = (idx & 7) * 8;
    u16x8 ve, vh;
    #pragma unroll
    for (int j = 0; j < 8; ++j) {
      ve[j] = te[oc + j][orow];
      vh[j] = th[oc + j][orow];
    }
    size_t o = ((size_t)b * 256 + c0 + orow) * 6144 + r0 + oc;
    *(u16x8*)(eVT + o) = ve;
    *(u16x8*)(yhi + o) = vh;
  }
}

// ---------------------------------------------------------------------------
// Merged rsc_cvt (sum S slabs, scale, cvt to bf16 hi).
// ---------------------------------------------------------------------------
static __device__ __forceinline__ void rsc_body(
    const float* in, unsigned short* out_hi, const float* h,
    int S, int R, int P, int bid, int nblk) {
  const long long qP = P >> 2;
  const long long nq = 2LL * R * qP;
  long long i = (long long)bid * 256 + threadIdx.x;
  const long long stride = (long long)nblk * 256;
  for (; i < nq; i += stride) {
    long long b = i / (R * qP);
    long long rem = i - b * (R * qP);
    int row = (int)(rem / qP);
    long long qc = rem - (long long)row * qP;
    const f32x4* base = (const f32x4*)in + ((b * S) * R + row) * qP + qc;
    f32x4 v = base[0];
    for (int s = 1; s < S; ++s) v += base[(long long)s * R * qP];
    v *= *(const f32x4*)(h + ((size_t)b * 8 + (row >> 5)) * P + (qc << 2));
    u16x4 hh = {f2bf(v[0]), f2bf(v[1]), f2bf(v[2]), f2bf(v[3])};
    ((u16x4*)out_hi)[i] = hh;
  }
}

__global__ void rsc2(const float* in1, unsigned short* o1h, const float* hF,
                     const float* in3, unsigned short* o3h, const float* hV) {
  if (blockIdx.x < 2048)
    rsc_body(in1, o1h, hF, 6, 256, 4096, blockIdx.x, 2048);
  else
    rsc_body(in3, o3h, hV, 12, 256, 2048, blockIdx.x - 2048, 1024);
}

// ---------------------------------------------------------------------------
// Merged hval dots: blocks [0,3072) e/einv pairs from P1; [3072,5120) f pair
// from P3.
// ---------------------------------------------------------------------------
__global__ __launch_bounds__(256) void dots(
    const float* __restrict__ P1, float* __restrict__ hE, float* __restrict__ hEi,
    const float* __restrict__ P3, float* __restrict__ hF) {
  const int wv = threadIdx.x >> 6, lane = threadIdx.x & 63;
  if (blockIdx.x < 3072) {
    const int row = blockIdx.x * 4 + wv;
    const float* base = P1 + (size_t)row * 1280 + lane * 4;
    f32x4 qv = *(const f32x4*)(base);
    f32x4 kv = *(const f32x4*)(base + 256);
    float p = qv[0] * kv[0] + qv[1] * kv[1] + qv[2] * kv[2] + qv[3] * kv[3];
    p += __shfl_xor(p, 1); p += __shfl_xor(p, 2); p += __shfl_xor(p, 4);
    f32x4 q2 = *(const f32x4*)(base + 768);
    f32x4 k2 = *(const f32x4*)(base + 1024);
    float p2 = q2[0] * k2[0] + q2[1] * k2[1] + q2[2] * k2[2] + q2[3] * k2[3];
    p2 += __shfl_xor(p2, 1); p2 += __shfl_xor(p2, 2); p2 += __shfl_xor(p2, 4);
    if ((lane & 7) == 0) {
      const int head = lane >> 3;
      const int b = row / 6144, pos = row % 6144;
      hE[((size_t)b * 8 + head) * 6144 + pos] = p * 0.17677669529663687f;
      hEi[((size_t)b * 8 + head) * 6144 + pos] = p2 * 0.17677669529663687f;
    }
  } else {
    const int row = (blockIdx.x - 3072) * 4 + wv;
    const float* base = P3 + (size_t)row * 512 + lane * 4;
    f32x4 qv = *(const f32x4*)(base);
    f32x4 kv = *(const f32x4*)(base + 256);
    float p = qv[0] * kv[0] + qv[1] * kv[1] + qv[2] * kv[2] + qv[3] * kv[3];
    p += __shfl_xor(p, 1); p += __shfl_xor(p, 2); p += __shfl_xor(p, 4);
    if ((lane & 7) == 0) {
      const int head = lane >> 3;
      const int b = row / 4096, pos = row % 4096;
      hF[((size_t)b * 8 + head) * 4096 + pos] = p * 0.17677669529663687f;
    }
  }
}

// ---------------------------------------------------------------------------
extern "C" void kernel_launch(void* const* d_in, const int* in_sizes, int n_in,
                              void* d_out, int out_size, void* d_ws, size_t ws_size,
                              hipStream_t stream) {
  const float* x_v = (const float*)d_in[0];
  const float* x_e = (const float*)d_in[1];
  const float* x_f = (const float*)d_in[2];
  const float* d0  = (const float*)d_in[3];   // (2, 6144, 2048)
  const float* d1  = (const float*)d_in[4];   // (2, 4096, 6144)
  float* out = (float*)d_out;

  const int NV = 2048, ME = 6144, KF = 4096;
  const unsigned short* NUS = nullptr;

  char* ws = (char*)d_ws;
  size_t o = 0;
  auto alloc = [&](size_t bytes) { size_t r = o; o = (o + bytes + 255) & ~255ULL; return r; };

  unsigned short* Wcat5_hi = (unsigned short*)(ws + alloc(1280 * 256 * 2));
  unsigned short* Wcat5_lo = (unsigned short*)(ws + alloc(1280 * 256 * 2));
  unsigned short* W3_hi = (unsigned short*)(ws + alloc(512 * 256 * 2));
  unsigned short* Wo_hi = (unsigned short*)(ws + alloc(256 * 256 * 2));
  unsigned short* Wo_lo = (unsigned short*)(ws + alloc(256 * 256 * 2));
  float* pHvE  = (float*)(ws + alloc(2 * 8 * ME * 4));
  float* pHvEi = (float*)(ws + alloc(2 * 8 * ME * 4));
  float* pHvF  = (float*)(ws + alloc(2 * 8 * KF * 4));
  float* pHvV  = (float*)(ws + alloc(2 * 8 * NV * 4));
  unsigned short* d1T_hi = (unsigned short*)(ws + alloc((size_t)2 * ME * KF * 2));   // [2][6144][4096]
  unsigned short* d1N_hi = (unsigned short*)(ws + alloc((size_t)2 * KF * ME * 2));   // [2][4096][6144]
  unsigned short* d0T_hi = (unsigned short*)(ws + alloc((size_t)2 * NV * ME * 2));   // [2][2048][6144]
  unsigned short* d0N_hi = (unsigned short*)(ws + alloc((size_t)2 * ME * NV * 2));   // [2][6144][2048]
  unsigned short* eVT_hi = (unsigned short*)(ws + alloc((size_t)2 * 256 * ME * 2));  // [2][256][6144]
  unsigned short* Y0T_hi = (unsigned short*)(ws + alloc((size_t)2 * 256 * ME * 2));
  unsigned short* T1sT_hi = (unsigned short*)(ws + alloc((size_t)2 * 256 * KF * 2)); // [2][256][4096]
  unsigned short* T3sT_hi = (unsigned short*)(ws + alloc((size_t)2 * 256 * NV * 2)); // [2][256][2048]
  float* pP1 = (float*)(ws + alloc((size_t)12288 * 1280 * 4));
  float* pP3 = (float*)(ws + alloc((size_t)8192 * 512 * 4));
  float* pTp1 = (float*)(ws + alloc((size_t)2 * 6 * 256 * KF * 4));   // T1^T slabs
  float* pTp3 = (float*)(ws + alloc((size_t)2 * 12 * 256 * NV * 4));  // T3^T slabs
  float* pT2p = (float*)(ws + alloc((size_t)2 * 4 * ME * 256 * 4));
  float* pT4p = (float*)(ws + alloc((size_t)2 * 4 * ME * 256 * 4));

  dim3 blk(256);

  // --- mega-prep ---
  PrepArgs pa;
  pa.wsrc[0] = (const float*)d_in[7];  pa.wh[0] = Wcat5_hi;          pa.wl[0] = Wcat5_lo;
  pa.wsrc[1] = (const float*)d_in[8];  pa.wh[1] = Wcat5_hi + 65536;  pa.wl[1] = Wcat5_lo + 65536;
  pa.wsrc[2] = (const float*)d_in[11]; pa.wh[2] = Wcat5_hi + 131072; pa.wl[2] = Wcat5_lo + 131072;
  pa.wsrc[3] = (const float*)d_in[9];  pa.wh[3] = Wcat5_hi + 196608; pa.wl[3] = Wcat5_lo + 196608;
  pa.wsrc[4] = (const float*)d_in[10]; pa.wh[4] = Wcat5_hi + 262144; pa.wl[4] = Wcat5_lo + 262144;
  pa.wsrc[5] = (const float*)d_in[12]; pa.wh[5] = W3_hi;             pa.wl[5] = nullptr;
  pa.wsrc[6] = (const float*)d_in[13]; pa.wh[6] = W3_hi + 65536;     pa.wl[6] = nullptr;
  pa.wsrc[7] = (const float*)d_in[14]; pa.wh[7] = Wo_hi;             pa.wl[7] = Wo_lo;
  pa.d1 = d1; pa.d1T = d1T_hi; pa.d1N = d1N_hi;
  pa.d0 = d0; pa.d0T_hi = d0T_hi; pa.d0N_hi = d0N_hi;
  pa.xv = x_v; pa.Wvq = (const float*)d_in[5]; pa.Wvk = (const float*)d_in[6];
  pa.hvV = pHvV;
  prep_all<<<19072, blk, 0, stream>>>(pa);

  // --- projections ---
  gemm_ws<true><<<dim3(96, 10, 1), blk, 0, stream>>>(
      x_e, Wcat5_hi, Wcat5_lo, pP1, 256, 256, 256, 0, 0, 0);
  gemm_ws<false><<<dim3(64, 4, 1), blk, 0, stream>>>(
      x_f, W3_hi, NUS, pP3, 256, 256, 256, 0, 0, 0);
  dots<<<5120, blk, 0, stream>>>(pP1, pHvE, pHvEi, pP3, pHvF);
  xpose_ev<<<dim3(96, 4, 2), blk, 0, stream>>>(pP1, eVT_hi, Y0T_hi, pHvE);

  // --- T1 + T3 in one launch (plain bf16) ---
  GJob jT1, jT3;
  jT1.Ah = eVT_hi; jT1.Bh = d1N_hi; jT1.C = pTp1;
  jT1.K = ME; jT1.ldA = ME; jT1.ldB = ME; jT1.S = 6; jT1.gx = 2; jT1.gy = 32;
  jT1.sA = 256LL * ME; jT1.sB = (long long)KF * ME; jT1.sC = 256LL * KF;
  jT3.Ah = Y0T_hi; jT3.Bh = d0T_hi; jT3.C = pTp3;
  jT3.K = ME; jT3.ldA = ME; jT3.ldB = ME; jT3.S = 12; jT3.gx = 2; jT3.gy = 16;
  jT3.sA = 256LL * ME; jT3.sB = (long long)NV * ME; jT3.sC = 256LL * NV;
  gemm_dual<true><<<1536, blk, 0, stream>>>(jT1, jT3, 768);

  // --- reductions + scale + cvt ---
  rsc2<<<3072, blk, 0, stream>>>(pTp1, T1sT_hi, pHvF, pTp3, T3sT_hi, pHvV);

  // --- T2 + T4 in one launch (plain bf16) ---
  GJob jT2, jT4;
  jT2.Ah = d1T_hi; jT2.Bh = T1sT_hi; jT2.C = pT2p;
  jT2.K = KF; jT2.ldA = KF; jT2.ldB = KF; jT2.S = 4; jT2.gx = 48; jT2.gy = 2;
  jT2.sA = (long long)ME * KF; jT2.sB = 256LL * KF; jT2.sC = (long long)ME * 256;
  jT4.Ah = d0N_hi; jT4.Bh = T3sT_hi; jT4.C = pT4p;
  jT4.K = NV; jT4.ldA = NV; jT4.ldB = NV; jT4.S = 4; jT4.gx = 48; jT4.gy = 2;
  jT4.sA = (long long)ME * NV; jT4.sB = 256LL * NV; jT4.sC = (long long)ME * 256;
  gemm_dual<false><<<1536, blk, 0, stream>>>(jT2, jT4, 768);

  // --- fused combine + output projection (split) ---
  gemm_out<<<dim3(96, 2, 1), blk, 0, stream>>>(pT2p, pT4p, pHvEi, Wo_hi, Wo_lo, out);
}